// Round 12
// baseline (874.856 us; speedup 1.0000x reference)
//
#include <hip/hip_runtime.h>
#include <hip/hip_bf16.h>
#include <math.h>

typedef __attribute__((ext_vector_type(4))) float fvec4;
typedef __attribute__((ext_vector_type(16))) float f32x16;
typedef __attribute__((ext_vector_type(4))) int ivec4;
typedef __attribute__((ext_vector_type(4))) unsigned short usvec4;
typedef __attribute__((ext_vector_type(8))) short bf16x8;

#define SEQ 2048
#define DMODEL 2048
#define DINNER 4096
#define DSTATE 16
#define DTRANK 128
#define NB 4
#define MROWS (NB*SEQ)  // 8192
#define NCHUNK 16
#define LC (SEQ/NCHUNK) // 128

__device__ __forceinline__ float bf2f(unsigned short h){
  union{unsigned int u; float f;} v; v.u = ((unsigned int)h)<<16; return v.f;
}
__device__ __forceinline__ unsigned short f2bf(float f){
  union{float f; unsigned int u;} v; v.f=f;
  unsigned int r = v.u + 0x7fffu + ((v.u>>16)&1u);
  return (unsigned short)(r>>16);
}
__device__ __forceinline__ void async16(const void* g, void* l){
  __builtin_amdgcn_global_load_lds((const __attribute__((address_space(1))) void*)g,
                                   (__attribute__((address_space(3))) void*)l, 16, 0, 0);
}
__device__ __forceinline__ float sigf(float x){ return 1.f/(1.f+__expf(-x)); }

__device__ __forceinline__ void cvt4(const float* s, unsigned short* d, int i){
  fvec4 v = *(const fvec4*)(s + i);
  usvec4 o;
  o[0]=f2bf(v[0]); o[1]=f2bf(v[1]); o[2]=f2bf(v[2]); o[3]=f2bf(v[3]);
  *(usvec4*)(d + i) = o;
}

// ---------------- fused fp32 -> bf16 converts ----------------
__global__ void cvt2_kernel(const float* __restrict__ a, unsigned short* __restrict__ oa,
                            const float* __restrict__ b, unsigned short* __restrict__ ob, int n){
  int i = (blockIdx.x*256 + threadIdx.x)*4;
  if (i < n) cvt4(a, oa, i);
  else       cvt4(b, ob, i - n);
}
__global__ void cvt3_kernel(const float* __restrict__ a, unsigned short* __restrict__ oa, int na,
                            const float* __restrict__ b, unsigned short* __restrict__ ob, int nb,
                            const float* __restrict__ c, unsigned short* __restrict__ oc, int nc){
  int i = (blockIdx.x*256 + threadIdx.x)*4;
  if (i < na){ cvt4(a, oa, i); return; }
  i -= na;
  if (i < nb){ cvt4(b, ob, i); return; }
  i -= nb;
  if (i < nc) cvt4(c, oc, i);
}

// ============ 256x256 GEMM (C = A * B^T), BK=64 2-slot, 32x32x16 MFMA =======
// r11 ring/sync/swizzle kept verbatim; inner math switched 16x16x32 ->
// 32x32x16 (measured ceiling 2382-2495 TF vs 2075 — ~18% lower cyc/FLOP at
// IDENTICAL LDS bytes/FLOP and identical 128 acc regs).
// Wave tile 128x64 = 4(M) x 2(N) fragments of 32x32. Per K-tile: 4 ksub
// clusters x 8 MFMA; reads for cluster s+1 issued before cluster s's MFMAs
// (r11's proven read-ahead; lgkm waits are counted, drain under MFMA).
// Operand frag (32x32x16): row/col = lane&31, k-chunk = (lane>>5)*8.
// C/D (verified m74/m101): col=lane&31, row=(q&3)+8*(q>>2)+4*(lane>>5).
// Swizzle: slot = (2s + (lane>>5)) ^ (row&7) — 8 lanes/slot = 2/bank = free;
// same involution pre-applied to global staging source (LDS dest linear).
// Race-freedom identical to r11 (one {vmcnt(0); barrier} per K-tile; the
// waited loads were issued one full iter earlier).
// (512,2): 256-reg budget: acc 128 + frags 48 + addr ~25.
// MODE 0: split x/z bf16 at col 4096 (in_proj). MODE 3: fp32 store (out_proj).
template<int MODE>
__global__ __launch_bounds__(512, 2) void gemm256(
    const unsigned short* __restrict__ A,
    const unsigned short* __restrict__ B,
    int K, int nbx, int ldc,
    unsigned short* __restrict__ Cb1,
    unsigned short* __restrict__ Cb2,
    float* __restrict__ Cf)
{
  __shared__ __align__(16) unsigned short lds[65536];  // 128 KiB: 2 x 64 KiB
  char* ldsc = (char*)lds;
  const int t = threadIdx.x;

  // T1: XCD swizzle (gridDim.x % 8 == 0 for all uses)
  const int nwg = gridDim.x;
  const int cpx = nwg >> 3;
  const int bid = blockIdx.x;
  const int swzb = (bid & 7)*cpx + (bid >> 3);
  const int bx = swzb % nbx, by = swzb / nbx;

  // staging (per slot: A[256][64] bf16 @0 (32KB, 128B rows), B @32768).
  const int r0 = t>>3;
  const int cel = ((t&7) ^ (r0&7)) * 8;
  const unsigned short* gA = A + (long)by*256*K + (long)r0*K + cel;
  const unsigned short* gB = B + (long)bx*256*K + (long)r0*K + cel;
  const long P64 = 64L*K;

  const int wid = t>>6, lane = t&63;
  const int wm = wid>>2, wn = wid&3;
  const int l31 = lane&31, lhi = lane>>5;
  // swizzled byte offset within a row for ksub s:
  // xs[s] = ((2s + lhi) ^ (lane&7)) << 4
  int xs[4];
  #pragma unroll
  for (int s=0;s<4;s++) xs[s] = (((2*s + lhi) ^ (lane&7)) << 4);
  // row byte bases: A frag i at row wm*128 + i*32 + l31; B frag j at
  // 32768 + (wn*64 + j*32 + l31)*128
  const int aB = (wm*128 + l31)*128;           // + i*4096
  const int bB = 32768 + (wn*64 + l31)*128;    // + j*4096

  f32x16 acc[4][2];
  #pragma unroll
  for (int i=0;i<4;i++){
    #pragma unroll
    for (int j=0;j<2;j++) acc[i][j] = (f32x16)(0.f);
  }

  const int NKT = K >> 6;
  auto stage = [&](int slot, int k0){
    char* sb = ldsc + slot*65536;
    #pragma unroll
    for (int p=0;p<4;p++) async16(gA + p*P64 + k0, sb + p*8192 + t*16);
    #pragma unroll
    for (int p=0;p<4;p++) async16(gB + p*P64 + k0, sb + 32768 + p*8192 + t*16);
  };

  stage(0, 0);   // prologue: tile 0 into slot 0

  bf16x8 aP[4], aQ[4], bU[2], bV[2];
#define RD(AF, BF, S) { \
    _Pragma("unroll") for (int i=0;i<4;i++) AF[i] = *(const bf16x8*)(cs + aB + i*4096 + xs[S]); \
    _Pragma("unroll") for (int j=0;j<2;j++) BF[j] = *(const bf16x8*)(cs + bB + j*4096 + xs[S]); }
#define MM(AF, BF) { \
    __builtin_amdgcn_s_setprio(1); \
    _Pragma("unroll") for (int i=0;i<4;i++){ \
      _Pragma("unroll") for (int j=0;j<2;j++) \
        acc[i][j] = __builtin_amdgcn_mfma_f32_32x32x16_bf16(AF[i], BF[j], acc[i][j], 0,0,0); } \
    __builtin_amdgcn_s_setprio(0); }

  for (int kt = 0; kt < NKT; ++kt){
    const char* cs = ldsc + (kt&1)*65536;
    asm volatile("s_waitcnt vmcnt(0)" ::: "memory");  // tile kt staged (only kt's 8 outstanding)
    __builtin_amdgcn_s_barrier();                     // staged chip-wide; other slot's readers done
    __builtin_amdgcn_sched_barrier(0);
    if (kt+1 < NKT) stage((kt+1)&1, (kt+1)*64);       // prefetch next tile
    __builtin_amdgcn_sched_barrier(0);
    RD(aP, bU, 0);
    RD(aQ, bV, 1);      // cluster-1 read-ahead
    MM(aP, bU);         // cluster 0
    RD(aP, bU, 2);      // cluster-2 read-ahead
    MM(aQ, bV);         // cluster 1
    RD(aQ, bV, 3);      // cluster-3 read-ahead
    MM(aP, bU);         // cluster 2
    MM(aQ, bV);         // cluster 3
  }
#undef RD
#undef MM

  const long crow0 = (long)by*256 + wm*128;
  const int  ccol0 = bx*256 + wn*64;
  #pragma unroll
  for (int i=0;i<4;i++){
    #pragma unroll
    for (int j=0;j<2;j++){
      #pragma unroll
      for (int q=0;q<16;q++){
        long rg = crow0 + i*32 + (q&3) + 8*(q>>2) + 4*lhi;
        int  cg = ccol0 + j*32 + l31;
        float v = acc[i][j][q];
        if (MODE==0){
          if (cg < DINNER) Cb1[rg*DINNER + cg] = f2bf(v);
          else             Cb2[rg*DINNER + (cg-DINNER)] = f2bf(v);
        } else {
          Cf[rg*(long)ldc + cg] = v;
        }
      }
    }
  }
}

// ---------------- m97-style 128x128 GEMM for the small projections ----------------
// MODE 2: softplus(v+bias) -> bf16 (dt_proj -> delta)
// MODE 4: split-K partial fp32 store (x_proj), z = blockIdx.z K-slice
template<int MODE>
__global__ __launch_bounds__(256) void gemm_bt(
    const unsigned short* __restrict__ A,
    const unsigned short* __restrict__ B,
    int lda, int Kloop, int Nreal,
    float* __restrict__ Cf,
    unsigned short* __restrict__ Cb1,
    const float* __restrict__ bias,
    int ldc)
{
  __shared__ __align__(16) unsigned short As[128*32];
  __shared__ __align__(16) unsigned short Bs[128*32];
  const int t = threadIdx.x;
  const int bx = blockIdx.x, by = blockIdx.y;
  const long koff = (MODE==4) ? (long)blockIdx.z * Kloop : 0;
  const int wave = t>>6, lane = t&63;
  const int wr = (wave>>1)*64, wc = (wave&1)*64;
  const int fr = lane&15, fc = lane>>4;
  fvec4 acc[4][4];
  #pragma unroll
  for(int i=0;i<4;i++){
    #pragma unroll
    for(int j=0;j<4;j++){ acc[i][j] = (fvec4)(0.f); }
  }
  const int srow = t>>2;
  const int scol = (t&3)*8;
  long rowA = (long)by*128 + srow;
  int rB0 = bx*128 + srow;      if (rB0 > Nreal-1) rB0 = Nreal-1;
  int rB1 = bx*128 + 64 + srow; if (rB1 > Nreal-1) rB1 = Nreal-1;
  const unsigned short* gA0 = A + rowA*(long)lda + scol + koff;
  const unsigned short* gA1 = gA0 + 64L*lda;
  const unsigned short* gB0 = B + (long)rB0*lda + scol + koff;
  const unsigned short* gB1 = B + (long)rB1*lda + scol + koff;
  unsigned short* lA0 = &As[t*8];
  unsigned short* lA1 = &As[2048 + t*8];
  unsigned short* lB0 = &Bs[t*8];
  unsigned short* lB1 = &Bs[2048 + t*8];

  for (int k0 = 0; k0 < Kloop; k0 += 32){
    async16(gA0 + k0, lA0);
    async16(gA1 + k0, lA1);
    async16(gB0 + k0, lB0);
    async16(gB1 + k0, lB1);
    __syncthreads();
    bf16x8 af[4], bv[4];
    #pragma unroll
    for(int i=0;i<4;i++){
      af[i] = *(const bf16x8*)&As[(wr + i*16 + fr)*32 + fc*8];
      bv[i] = *(const bf16x8*)&Bs[(wc + i*16 + fr)*32 + fc*8];
    }
    #pragma unroll
    for(int i=0;i<4;i++){
      #pragma unroll
      for(int j=0;j<4;j++){
        acc[i][j] = __builtin_amdgcn_mfma_f32_16x16x32_bf16(af[i], bv[j], acc[i][j], 0,0,0);
      }
    }
    __syncthreads();
  }

  const long crow0 = (long)by*128 + wr;
  const int ccol0 = bx*128 + wc;
  float* Cfz = (MODE==4) ? (Cf + (long)blockIdx.z * MROWS * ldc) : Cf;
  #pragma unroll
  for(int i=0;i<4;i++){
    #pragma unroll
    for(int j=0;j<4;j++){
      #pragma unroll
      for(int q=0;q<4;q++){
        long rg = crow0 + i*16 + fc*4 + q;
        int  cg = ccol0 + j*16 + fr;
        float v = acc[i][j][q];
        if (MODE==4){
          if (cg < Nreal) Cfz[rg*ldc + cg] = v;
        } else if (MODE==2){
          float x = v + bias[cg];
          float sp = (x > 20.f) ? x : log1pf(__expf(x));
          Cb1[rg*ldc + cg] = f2bf(sp);
        }
      }
    }
  }
}

// ---------------- reduce x_proj partials + emit dtr bf16 ----------------
__global__ void reduce_xproj(const float* __restrict__ part,
                             float* __restrict__ xdbl,
                             unsigned short* __restrict__ dtr){
  int i = blockIdx.x*256 + threadIdx.x;           // x4 elems, 8192*160/4 total
  long base = (long)i*4;
  fvec4 s = *(const fvec4*)&part[base];
  #pragma unroll
  for (int z=1; z<4; z++){
    fvec4 p = *(const fvec4*)&part[(long)z*MROWS*160 + base];
    s[0]+=p[0]; s[1]+=p[1]; s[2]+=p[2]; s[3]+=p[3];
  }
  *(fvec4*)&xdbl[base] = s;
  long mrow = base / 160;
  int c = (int)(base - mrow*160);
  if (c < DTRANK){
    usvec4 o; o[0]=f2bf(s[0]); o[1]=f2bf(s[1]); o[2]=f2bf(s[2]); o[3]=f2bf(s[3]);
    *(usvec4*)&dtr[mrow*DTRANK + c] = o;
  }
}

// ------- depthwise causal conv(4) + bias + SiLU (+ fused conv_state) -------
__global__ __launch_bounds__(256) void conv_silu_kernel(
    const unsigned short* __restrict__ xb, const float* __restrict__ w,
    const float* __restrict__ bias, unsigned short* __restrict__ ub,
    float* __restrict__ cs_out)
{
  int gid = blockIdx.x*256 + threadIdx.x;
  int d0 = (gid & 511)*8;
  long m = gid >> 9;
  int l = (int)(m & (SEQ-1));
  fvec4 w4[8];
  #pragma unroll
  for(int k=0;k<8;k++) w4[k] = *(const fvec4*)&w[(d0+k)*4];
  float acc[8];
  fvec4 b0 = *(const fvec4*)&bias[d0];
  fvec4 b1 = *(const fvec4*)&bias[d0+4];
  acc[0]=b0[0];acc[1]=b0[1];acc[2]=b0[2];acc[3]=b0[3];
  acc[4]=b1[0];acc[5]=b1[1];acc[6]=b1[2];acc[7]=b1[3];
  float xcur[8];
  #pragma unroll
  for(int j=0;j<4;j++){
    int lj = l-3+j;
    if (lj >= 0){
      ivec4 xv = *(const ivec4*)&xb[(m-3+j)*DINNER + d0];
      float xs[8];
      #pragma unroll
      for(int q=0;q<4;q++){
        unsigned int wd = (unsigned int)xv[q];
        xs[2*q]   = bf2f((unsigned short)(wd & 0xffffu));
        xs[2*q+1] = bf2f((unsigned short)(wd >> 16));
      }
      #pragma unroll
      for(int k=0;k<8;k++) acc[k] += xs[k]*w4[k][j];
      if (j==3){
        #pragma unroll
        for(int k=0;k<8;k++) xcur[k] = xs[k];
      }
    }
  }
  if (l >= SEQ-4){
    int b = (int)(m >> 11);
    int jj = l - (SEQ-4);
    #pragma unroll
    for(int k=0;k<8;k++) cs_out[b*16384 + (d0+k)*4 + jj] = xcur[k];
  }
  ivec4 ov;
  #pragma unroll
  for(int q=0;q<4;q++){
    float y0 = acc[2*q]  * sigf(acc[2*q]);
    float y1 = acc[2*q+1]* sigf(acc[2*q+1]);
    ov[q] = (int)((unsigned)f2bf(y0) | ((unsigned)f2bf(y1) << 16));
  }
  *(ivec4*)&ub[m*DINNER + d0] = ov;
}

// ---- exp(dl*a[n]) for a[n] == -(n+1): powers of e1=exp(-dl) ----
__device__ __forceinline__ void exp_powers(float dl, float* e){
  float e1 = __expf(-dl);
  float p2 = e1*e1, p3 = p2*e1, p4 = p2*p2;
  float p5 = p4*e1, p6 = p4*p2, p7 = p4*p3, p8 = p4*p4;
  e[0]=e1; e[1]=p2; e[2]=p3; e[3]=p4; e[4]=p5; e[5]=p6; e[6]=p7; e[7]=p8;
  e[8]=p8*e1; e[9]=p8*p2; e[10]=p8*p3; e[11]=p8*p4;
  e[12]=p8*p5; e[13]=p8*p6; e[14]=p8*p7; e[15]=p8*p8;
}

// ================= chunked parallel scan =================
__global__ __launch_bounds__(256) void scan_part1(
    const unsigned short* __restrict__ delta_b,
    const unsigned short* __restrict__ u_b,
    const float* __restrict__ xdbl,
    const float* __restrict__ Amat,
    float* __restrict__ S,
    float* __restrict__ sdelta)
{
  const int t = threadIdx.x;
  const int blk = blockIdx.x;
  const int c = blk & 15, b = (blk>>4)&3, d = (blk>>6)*256 + t;
  float a[16], s[16];
  #pragma unroll
  for (int n=0;n<16;n++){ a[n] = Amat[n*DINNER+d]; s[n]=0.f; }
  bool powA = true;
  #pragma unroll
  for (int n=0;n<16;n++) powA = powA && (a[n] == -(float)(n+1));
  float sd = 0.f;
  const long mbase = (long)b*SEQ + c*LC;

#define S1_BODY(EXPR_E) \
  for (int l=0;l<LC;l++){ \
    long m = mbase + l; \
    float dl = bf2f(delta_b[m*DINNER+d]); \
    float ul = bf2f(u_b[m*DINNER+d]); \
    const float* xb = &xdbl[m*160 + 128]; \
    float dbu = dl*ul; \
    sd += dl; \
    float e[16]; EXPR_E; \
    _Pragma("unroll") \
    for (int g=0; g<4; g++){ \
      fvec4 Bg = *(const fvec4*)(xb + 4*g); \
      _Pragma("unroll") \
      for (int q=0;q<4;q++){ \
        int n = g*4+q; \
        s[n] = e[n]*s[n] + Bg[q]*dbu; \
      } \
    } \
  }

  if (powA){
    S1_BODY(exp_powers(dl, e))
  } else {
    S1_BODY({ _Pragma("unroll") for (int n=0;n<16;n++) e[n] = __expf(dl*a[n]); })
  }
#undef S1_BODY

  const long base = ((long)(b*NCHUNK + c)*DSTATE)*DINNER + d;
  #pragma unroll
  for (int n=0;n<16;n++) S[base + (long)n*DINNER] = s[n];
  sdelta[(long)(b*NCHUNK+c)*DINNER + d] = sd;
}

__global__ __launch_bounds__(256) void scan_part2(
    const float* __restrict__ S,
    const float* __restrict__ sdelta,
    const float* __restrict__ Amat,
    float* __restrict__ Xin,
    float* __restrict__ last_state)
{
  int id = blockIdx.x*256 + threadIdx.x;
  int d = id & (DINNER-1);
  int n = (id>>12) & 15;
  int b = id>>16;
  float a = Amat[n*DINNER+d];
  float X = 0.f;
  #pragma unroll
  for (int c=0;c<NCHUNK;c++){
    long sb = ((long)(b*NCHUNK+c)*DSTATE + n)*DINNER + d;
    Xin[sb] = X;
    float sd = sdelta[(long)(b*NCHUNK+c)*DINNER + d];
    float Sc = S[sb];
    X = __expf(a*sd)*X + Sc;
  }
  last_state[((long)b*DSTATE + n)*DINNER + d] = X;
}

__global__ __launch_bounds__(256) void scan_part3(
    const unsigned short* __restrict__ delta_b,
    const unsigned short* __restrict__ u_b,
    const unsigned short* __restrict__ z_b,
    const float* __restrict__ xdbl,
    const float* __restrict__ Amat,
    const float* __restrict__ Dvec,
    const float* __restrict__ Xin,
    unsigned short* __restrict__ y_b)
{
  const int t = threadIdx.x;
  const int blk = blockIdx.x;
  const int c = blk & 15, b = (blk>>4)&3, d = (blk>>6)*256 + t;
  float a[16], s[16];
  const long xb0 = ((long)(b*NCHUNK + c)*DSTATE)*DINNER + d;
  #pragma unroll
  for (int n=0;n<16;n++){
    a[n] = Amat[n*DINNER+d];
    s[n] = Xin[xb0 + (long)n*DINNER];
  }
  bool powA = true;
  #pragma unroll
  for (int n=0;n<16;n++) powA = powA && (a[n] == -(float)(n+1));
  const float Dd = Dvec[d];
  const long mbase = (long)b*SEQ + c*LC;

#define S3_BODY(EXPR_E) \
  for (int l=0;l<LC;l++){ \
    long m = mbase + l; \
    float dl = bf2f(delta_b[m*DINNER+d]); \
    float ul = bf2f(u_b[m*DINNER+d]); \
    float zl = bf2f(z_b[m*DINNER+d]); \
    const float* xb = &xdbl[m*160 + 128]; \
    float dbu = dl*ul; \
    float y = 0.f; \
    float e[16]; EXPR_E; \
    _Pragma("unroll") \
    for (int g=0; g<4; g++){ \
      fvec4 Bg = *(const fvec4*)(xb + 4*g); \
      fvec4 Cg = *(const fvec4*)(xb + 16 + 4*g); \
      _Pragma("unroll") \
      for (int q=0;q<4;q++){ \
        int n = g*4+q; \
        s[n] = e[n]*s[n] + Bg[q]*dbu; \
        y += Cg[q]*s[n]; \
      } \
    } \
    float yy = y + ul*Dd; \
    float zs = zl*sigf(zl); \
    y_b[m*DINNER+d] = f2bf(yy*zs); \
  }

  if (powA){
    S3_BODY(exp_powers(dl, e))
  } else {
    S3_BODY({ _Pragma("unroll") for (int n=0;n<16;n++) e[n] = __expf(dl*a[n]); })
  }
#undef S3_BODY
}

// ---------------- launcher ----------------
// Aliased 256 MiB layout:
//   Slot A [0,64M):    hs_b(32M)+w_in_b(32M) -> xpart(21M, step 5-6) ->
//                      delta(64M, step 7+)
//   Slot B [64,128M):  x(64M) -> after conv: wxp@64 wdt@66 wout@68 xdbl@84
//                      dtr@90 S@92(16M) Xin@108(16M) sdelta@124(1M)
//   Slot C [128,192M): z(64M)
//   Slot D [192,256M): u(64M) -> y written in-place by scan_part3
extern "C" void kernel_launch(void* const* d_in, const int* in_sizes, int n_in,
                              void* d_out, int out_size, void* d_ws, size_t ws_size,
                              hipStream_t stream) {
  const float* hs     = (const float*)d_in[0];
  const float* w_in   = (const float*)d_in[6];
  const float* conv_w = (const float*)d_in[7];
  const float* conv_b = (const float*)d_in[8];
  const float* w_xp   = (const float*)d_in[9];
  const float* w_dt   = (const float*)d_in[10];
  const float* dt_bias= (const float*)d_in[11];
  const float* Amat   = (const float*)d_in[12];
  const float* Dvec   = (const float*)d_in[13];
  const float* w_out  = (const float*)d_in[14];
  float* out = (float*)d_out;

  char* ws = (char*)d_ws;
  const size_t MiB = (size_t)1 << 20;

  unsigned short *hs_b, *w_in_b, *x_b, *z_b, *u_b, *delta_b;
  unsigned short *wxp_b, *wdt_b, *wout_b, *dtr_b, *y_b;
  float *xdbl, *Sbuf, *Xin, *sdelta, *xpart;

  if (ws_size >= 424*MiB){
    size_t off = 0;
    auto alloc = [&](size_t bytes)->void*{ void* p = ws + off; off += (bytes + 255) & ~(size_t)255; return p; };
    hs_b   = (unsigned short*)alloc((size_t)MROWS*DMODEL*2);
    w_in_b = (unsigned short*)alloc((size_t)2*DINNER*DMODEL*2);
    x_b    = (unsigned short*)alloc((size_t)MROWS*DINNER*2);
    z_b    = (unsigned short*)alloc((size_t)MROWS*DINNER*2);
    u_b    = (unsigned short*)alloc((size_t)MROWS*DINNER*2);
    delta_b= (unsigned short*)alloc((size_t)MROWS*DINNER*2);
    wxp_b  = (unsigned short*)alloc((size_t)160*DINNER*2);
    wdt_b  = (unsigned short*)alloc((size_t)DINNER*DTRANK*2);
    wout_b = (unsigned short*)alloc((size_t)DMODEL*DINNER*2);
    xdbl   = (float*)alloc((size_t)MROWS*160*4);
    dtr_b  = (unsigned short*)alloc((size_t)MROWS*DTRANK*2);
    Sbuf   = (float*)alloc((size_t)NB*NCHUNK*DSTATE*DINNER*4);
    Xin    = (float*)alloc((size_t)NB*NCHUNK*DSTATE*DINNER*4);
    sdelta = (float*)alloc((size_t)NB*NCHUNK*DINNER*4);
    xpart  = (float*)alloc((size_t)4*MROWS*160*4);
    y_b    = x_b;
  } else {
    hs_b    = (unsigned short*)(ws + 0);
    w_in_b  = (unsigned short*)(ws + 32*MiB);
    xpart   = (float*)         (ws + 0);   // steps 5-6 (hs/w_in dead)
    delta_b = (unsigned short*)(ws + 0);   // step 7+ (xpart dead)
    x_b     = (unsigned short*)(ws + 64*MiB);
    wxp_b   = (unsigned short*)(ws + 64*MiB);
    wdt_b   = (unsigned short*)(ws + 66*MiB);
    wout_b  = (unsigned short*)(ws + 68*MiB);
    xdbl    = (float*)         (ws + 84*MiB);
    dtr_b   = (unsigned short*)(ws + 90*MiB);
    Sbuf    = (float*)         (ws + 92*MiB);
    Xin     = (float*)         (ws + 108*MiB);
    sdelta  = (float*)         (ws + 124*MiB);
    z_b     = (unsigned short*)(ws + 128*MiB);
    u_b     = (unsigned short*)(ws + 192*MiB);
    y_b     = u_b;
  }

  // 1) converts needed for in_proj
  cvt2_kernel<<<(2*MROWS*DMODEL)/1024, 256, 0, stream>>>(hs, hs_b, w_in, w_in_b,
                                                         MROWS*DMODEL);
  // 2) in_proj: 256^2 tiles -> 32x32=1024 blocks (K=2048 -> NKT=32)
  gemm256<0><<<1024, 512, 0, stream>>>(hs_b, w_in_b, DMODEL, 32, 0,
                                       x_b, z_b, nullptr);
  // 3) conv + silu -> u, fused conv_state output (x dead afterwards)
  conv_silu_kernel<<<(MROWS*512)/256, 256, 0, stream>>>(x_b, conv_w, conv_b, u_b,
                                                        out + (size_t)MROWS*DMODEL);
  // 4) weight converts (one kernel, into dead-x slot in aliased mode)
  {
    int na = 160*DINNER, nb = DINNER*DTRANK, nc = DMODEL*DINNER;
    int tot4 = (na+nb+nc)/4;
    cvt3_kernel<<<(tot4+255)/256, 256, 0, stream>>>(w_xp, wxp_b, na,
                                                    w_dt, wdt_b, nb,
                                                    w_out, wout_b, nc);
  }
  // 5) x_proj split-K x4 -> partials
  gemm_bt<4><<<dim3(2,64,4), 256, 0, stream>>>(u_b, wxp_b, DINNER, 1024, 160,
                                               xpart, nullptr, nullptr, 160);
  // 6) reduce partials -> xdbl fp32 + dtr bf16
  reduce_xproj<<<(MROWS*160/4)/256, 256, 0, stream>>>(xpart, xdbl, dtr_b);
  // 7) dt_proj + softplus -> delta (m97-style)
  gemm_bt<2><<<dim3(32,64), 256, 0, stream>>>(dtr_b, wdt_b, DTRANK, DTRANK, DINNER,
                                              nullptr, delta_b, dt_bias, DINNER);
  // 8) chunked scan
  scan_part1<<<1024, 256, 0, stream>>>(delta_b, u_b, xdbl, Amat, Sbuf, sdelta);
  scan_part2<<<1024, 256, 0, stream>>>(Sbuf, sdelta, Amat, Xin,
                                       out + (size_t)MROWS*DMODEL + NB*DINNER*4);
  scan_part3<<<1024, 256, 0, stream>>>(delta_b, u_b, z_b, xdbl, Amat, Dvec, Xin, y_b);
  // 9) out_proj: 32x8=256 blocks (K=4096 -> NKT=64)
  gemm256<3><<<256, 512, 0, stream>>>(y_b, wout_b, DINNER, 8, DMODEL,
                                      nullptr, nullptr, out);
}

// Round 13
// 874.689 us; speedup vs baseline: 1.0002x; 1.0002x over previous
//
#include <hip/hip_runtime.h>
#include <hip/hip_bf16.h>
#include <math.h>

typedef __attribute__((ext_vector_type(4))) float fvec4;
typedef __attribute__((ext_vector_type(16))) float f32x16;
typedef __attribute__((ext_vector_type(4))) int ivec4;
typedef __attribute__((ext_vector_type(4))) unsigned short usvec4;
typedef __attribute__((ext_vector_type(8))) short bf16x8;

#define SEQ 2048
#define DMODEL 2048
#define DINNER 4096
#define DSTATE 16
#define DTRANK 128
#define NB 4
#define MROWS (NB*SEQ)  // 8192
#define NCHUNK 16
#define LC (SEQ/NCHUNK) // 128

__device__ __forceinline__ float bf2f(unsigned short h){
  union{unsigned int u; float f;} v; v.u = ((unsigned int)h)<<16; return v.f;
}
__device__ __forceinline__ unsigned short f2bf(float f){
  union{float f; unsigned int u;} v; v.f=f;
  unsigned int r = v.u + 0x7fffu + ((v.u>>16)&1u);
  return (unsigned short)(r>>16);
}
__device__ __forceinline__ void async16(const void* g, void* l){
  __builtin_amdgcn_global_load_lds((const __attribute__((address_space(1))) void*)g,
                                   (__attribute__((address_space(3))) void*)l, 16, 0, 0);
}
__device__ __forceinline__ float sigf(float x){ return 1.f/(1.f+__expf(-x)); }

__device__ __forceinline__ void cvt4(const float* s, unsigned short* d, int i){
  fvec4 v = *(const fvec4*)(s + i);
  usvec4 o;
  o[0]=f2bf(v[0]); o[1]=f2bf(v[1]); o[2]=f2bf(v[2]); o[3]=f2bf(v[3]);
  *(usvec4*)(d + i) = o;
}

// ---------------- fused fp32 -> bf16 converts ----------------
__global__ void cvt2_kernel(const float* __restrict__ a, unsigned short* __restrict__ oa,
                            const float* __restrict__ b, unsigned short* __restrict__ ob, int n){
  int i = (blockIdx.x*256 + threadIdx.x)*4;
  if (i < n) cvt4(a, oa, i);
  else       cvt4(b, ob, i - n);
}
__global__ void cvt3_kernel(const float* __restrict__ a, unsigned short* __restrict__ oa, int na,
                            const float* __restrict__ b, unsigned short* __restrict__ ob, int nb,
                            const float* __restrict__ c, unsigned short* __restrict__ oc, int nc){
  int i = (blockIdx.x*256 + threadIdx.x)*4;
  if (i < na){ cvt4(a, oa, i); return; }
  i -= na;
  if (i < nb){ cvt4(b, ob, i); return; }
  i -= nb;
  if (i < nc) cvt4(c, oc, i);
}

// ============ 256x256 GEMM (C = A * B^T), BK=64 2-slot, 32x32x16 MFMA =======
// r12 structure; swizzle key FIXED. r12's f(row)=row&7 was constant across a
// stride-8 lane group's 4 rows -> slots took 2 values x4 lanes = 4-way
// conflict (2.5e7 measured). New key injects row bits 3-4:
//   f(row) = (row&7) ^ (((row>>3)&3)<<1)
// Within any stride-8 group the 8 (row,chunk) pairs map to 8 distinct slots
// (k<<1 spans bits1-2, lhi spans bit0); consecutive-8 / 16-lane groupings
// stay <=2-way (free, m136). XOR is self-inverse, so the same key applied
// to the staging SOURCE keeps reads exact (key depends only on l31 bits for
// all frag rows: A row = wm*128+i*32+l31, B row = wn*64+j*32+l31, and on
// r0 bits for all staging passes: row = p*64+r0, p*64 = 0 mod 32).
// Everything else identical to r12/r11: one {vmcnt(0); barrier}/K-tile,
// read-ahead clusters, T1 XCD swizzle, (512,2).
// MODE 0: split x/z bf16 at col 4096 (in_proj). MODE 3: fp32 store (out_proj).
template<int MODE>
__global__ __launch_bounds__(512, 2) void gemm256(
    const unsigned short* __restrict__ A,
    const unsigned short* __restrict__ B,
    int K, int nbx, int ldc,
    unsigned short* __restrict__ Cb1,
    unsigned short* __restrict__ Cb2,
    float* __restrict__ Cf)
{
  __shared__ __align__(16) unsigned short lds[65536];  // 128 KiB: 2 x 64 KiB
  char* ldsc = (char*)lds;
  const int t = threadIdx.x;

  // T1: XCD swizzle (gridDim.x % 8 == 0 for all uses)
  const int nwg = gridDim.x;
  const int cpx = nwg >> 3;
  const int bid = blockIdx.x;
  const int swzb = (bid & 7)*cpx + (bid >> 3);
  const int bx = swzb % nbx, by = swzb / nbx;

  // staging (per slot: A[256][64] bf16 @0 (32KB, 128B rows), B @32768).
  // pass p: dest = p*8192 + t*16 (linear); row-within-pass r0 = t>>3;
  // source chunk = (t&7) ^ f(r0), f(r) = (r&7) ^ (((r>>3)&3)<<1).
  const int r0 = t>>3;
  const int fsw = (r0&7) ^ (((r0>>3)&3)<<1);
  const int cel = ((t&7) ^ fsw) * 8;
  const unsigned short* gA = A + (long)by*256*K + (long)r0*K + cel;
  const unsigned short* gB = B + (long)bx*256*K + (long)r0*K + cel;
  const long P64 = 64L*K;

  const int wid = t>>6, lane = t&63;
  const int wm = wid>>2, wn = wid&3;
  const int l31 = lane&31, lhi = lane>>5;
  // read: global chunk (2s+lhi) of row (..+l31) lives at slot (2s+lhi)^f(l31)
  const int frd = (l31&7) ^ (((l31>>3)&3)<<1);
  int xs[4];
  #pragma unroll
  for (int s=0;s<4;s++) xs[s] = (((2*s + lhi) ^ frd) << 4);
  const int aB = (wm*128 + l31)*128;           // + i*4096
  const int bB = 32768 + (wn*64 + l31)*128;    // + j*4096

  f32x16 acc[4][2];
  #pragma unroll
  for (int i=0;i<4;i++){
    #pragma unroll
    for (int j=0;j<2;j++) acc[i][j] = (f32x16)(0.f);
  }

  const int NKT = K >> 6;
  auto stage = [&](int slot, int k0){
    char* sb = ldsc + slot*65536;
    #pragma unroll
    for (int p=0;p<4;p++) async16(gA + p*P64 + k0, sb + p*8192 + t*16);
    #pragma unroll
    for (int p=0;p<4;p++) async16(gB + p*P64 + k0, sb + 32768 + p*8192 + t*16);
  };

  stage(0, 0);   // prologue: tile 0 into slot 0

  bf16x8 aP[4], aQ[4], bU[2], bV[2];
#define RD(AF, BF, S) { \
    _Pragma("unroll") for (int i=0;i<4;i++) AF[i] = *(const bf16x8*)(cs + aB + i*4096 + xs[S]); \
    _Pragma("unroll") for (int j=0;j<2;j++) BF[j] = *(const bf16x8*)(cs + bB + j*4096 + xs[S]); }
#define MM(AF, BF) { \
    __builtin_amdgcn_s_setprio(1); \
    _Pragma("unroll") for (int i=0;i<4;i++){ \
      _Pragma("unroll") for (int j=0;j<2;j++) \
        acc[i][j] = __builtin_amdgcn_mfma_f32_32x32x16_bf16(AF[i], BF[j], acc[i][j], 0,0,0); } \
    __builtin_amdgcn_s_setprio(0); }

  for (int kt = 0; kt < NKT; ++kt){
    const char* cs = ldsc + (kt&1)*65536;
    asm volatile("s_waitcnt vmcnt(0)" ::: "memory");  // tile kt staged (only kt's 8 outstanding)
    __builtin_amdgcn_s_barrier();                     // staged chip-wide; other slot's readers done
    __builtin_amdgcn_sched_barrier(0);
    if (kt+1 < NKT) stage((kt+1)&1, (kt+1)*64);       // prefetch next tile
    __builtin_amdgcn_sched_barrier(0);
    RD(aP, bU, 0);
    RD(aQ, bV, 1);      // cluster-1 read-ahead
    MM(aP, bU);         // cluster 0
    RD(aP, bU, 2);      // cluster-2 read-ahead
    MM(aQ, bV);         // cluster 1
    RD(aQ, bV, 3);      // cluster-3 read-ahead
    MM(aP, bU);         // cluster 2
    MM(aQ, bV);         // cluster 3
  }
#undef RD
#undef MM

  const long crow0 = (long)by*256 + wm*128;
  const int  ccol0 = bx*256 + wn*64;
  #pragma unroll
  for (int i=0;i<4;i++){
    #pragma unroll
    for (int j=0;j<2;j++){
      #pragma unroll
      for (int q=0;q<16;q++){
        long rg = crow0 + i*32 + (q&3) + 8*(q>>2) + 4*lhi;
        int  cg = ccol0 + j*32 + l31;
        float v = acc[i][j][q];
        if (MODE==0){
          if (cg < DINNER) Cb1[rg*DINNER + cg] = f2bf(v);
          else             Cb2[rg*DINNER + (cg-DINNER)] = f2bf(v);
        } else {
          Cf[rg*(long)ldc + cg] = v;
        }
      }
    }
  }
}

// ---------------- m97-style 128x128 GEMM for the small projections ----------------
// MODE 2: softplus(v+bias) -> bf16 (dt_proj -> delta)
// MODE 4: split-K partial fp32 store (x_proj), z = blockIdx.z K-slice
template<int MODE>
__global__ __launch_bounds__(256) void gemm_bt(
    const unsigned short* __restrict__ A,
    const unsigned short* __restrict__ B,
    int lda, int Kloop, int Nreal,
    float* __restrict__ Cf,
    unsigned short* __restrict__ Cb1,
    const float* __restrict__ bias,
    int ldc)
{
  __shared__ __align__(16) unsigned short As[128*32];
  __shared__ __align__(16) unsigned short Bs[128*32];
  const int t = threadIdx.x;
  const int bx = blockIdx.x, by = blockIdx.y;
  const long koff = (MODE==4) ? (long)blockIdx.z * Kloop : 0;
  const int wave = t>>6, lane = t&63;
  const int wr = (wave>>1)*64, wc = (wave&1)*64;
  const int fr = lane&15, fc = lane>>4;
  fvec4 acc[4][4];
  #pragma unroll
  for(int i=0;i<4;i++){
    #pragma unroll
    for(int j=0;j<4;j++){ acc[i][j] = (fvec4)(0.f); }
  }
  const int srow = t>>2;
  const int scol = (t&3)*8;
  long rowA = (long)by*128 + srow;
  int rB0 = bx*128 + srow;      if (rB0 > Nreal-1) rB0 = Nreal-1;
  int rB1 = bx*128 + 64 + srow; if (rB1 > Nreal-1) rB1 = Nreal-1;
  const unsigned short* gA0 = A + rowA*(long)lda + scol + koff;
  const unsigned short* gA1 = gA0 + 64L*lda;
  const unsigned short* gB0 = B + (long)rB0*lda + scol + koff;
  const unsigned short* gB1 = B + (long)rB1*lda + scol + koff;
  unsigned short* lA0 = &As[t*8];
  unsigned short* lA1 = &As[2048 + t*8];
  unsigned short* lB0 = &Bs[t*8];
  unsigned short* lB1 = &Bs[2048 + t*8];

  for (int k0 = 0; k0 < Kloop; k0 += 32){
    async16(gA0 + k0, lA0);
    async16(gA1 + k0, lA1);
    async16(gB0 + k0, lB0);
    async16(gB1 + k0, lB1);
    __syncthreads();
    bf16x8 af[4], bv[4];
    #pragma unroll
    for(int i=0;i<4;i++){
      af[i] = *(const bf16x8*)&As[(wr + i*16 + fr)*32 + fc*8];
      bv[i] = *(const bf16x8*)&Bs[(wc + i*16 + fr)*32 + fc*8];
    }
    #pragma unroll
    for(int i=0;i<4;i++){
      #pragma unroll
      for(int j=0;j<4;j++){
        acc[i][j] = __builtin_amdgcn_mfma_f32_16x16x32_bf16(af[i], bv[j], acc[i][j], 0,0,0);
      }
    }
    __syncthreads();
  }

  const long crow0 = (long)by*128 + wr;
  const int ccol0 = bx*128 + wc;
  float* Cfz = (MODE==4) ? (Cf + (long)blockIdx.z * MROWS * ldc) : Cf;
  #pragma unroll
  for(int i=0;i<4;i++){
    #pragma unroll
    for(int j=0;j<4;j++){
      #pragma unroll
      for(int q=0;q<4;q++){
        long rg = crow0 + i*16 + fc*4 + q;
        int  cg = ccol0 + j*16 + fr;
        float v = acc[i][j][q];
        if (MODE==4){
          if (cg < Nreal) Cfz[rg*ldc + cg] = v;
        } else if (MODE==2){
          float x = v + bias[cg];
          float sp = (x > 20.f) ? x : log1pf(__expf(x));
          Cb1[rg*ldc + cg] = f2bf(sp);
        }
      }
    }
  }
}

// ---------------- reduce x_proj partials + emit dtr bf16 ----------------
__global__ void reduce_xproj(const float* __restrict__ part,
                             float* __restrict__ xdbl,
                             unsigned short* __restrict__ dtr){
  int i = blockIdx.x*256 + threadIdx.x;           // x4 elems, 8192*160/4 total
  long base = (long)i*4;
  fvec4 s = *(const fvec4*)&part[base];
  #pragma unroll
  for (int z=1; z<4; z++){
    fvec4 p = *(const fvec4*)&part[(long)z*MROWS*160 + base];
    s[0]+=p[0]; s[1]+=p[1]; s[2]+=p[2]; s[3]+=p[3];
  }
  *(fvec4*)&xdbl[base] = s;
  long mrow = base / 160;
  int c = (int)(base - mrow*160);
  if (c < DTRANK){
    usvec4 o; o[0]=f2bf(s[0]); o[1]=f2bf(s[1]); o[2]=f2bf(s[2]); o[3]=f2bf(s[3]);
    *(usvec4*)&dtr[mrow*DTRANK + c] = o;
  }
}

// ------- depthwise causal conv(4) + bias + SiLU (+ fused conv_state) -------
__global__ __launch_bounds__(256) void conv_silu_kernel(
    const unsigned short* __restrict__ xb, const float* __restrict__ w,
    const float* __restrict__ bias, unsigned short* __restrict__ ub,
    float* __restrict__ cs_out)
{
  int gid = blockIdx.x*256 + threadIdx.x;
  int d0 = (gid & 511)*8;
  long m = gid >> 9;
  int l = (int)(m & (SEQ-1));
  fvec4 w4[8];
  #pragma unroll
  for(int k=0;k<8;k++) w4[k] = *(const fvec4*)&w[(d0+k)*4];
  float acc[8];
  fvec4 b0 = *(const fvec4*)&bias[d0];
  fvec4 b1 = *(const fvec4*)&bias[d0+4];
  acc[0]=b0[0];acc[1]=b0[1];acc[2]=b0[2];acc[3]=b0[3];
  acc[4]=b1[0];acc[5]=b1[1];acc[6]=b1[2];acc[7]=b1[3];
  float xcur[8];
  #pragma unroll
  for(int j=0;j<4;j++){
    int lj = l-3+j;
    if (lj >= 0){
      ivec4 xv = *(const ivec4*)&xb[(m-3+j)*DINNER + d0];
      float xsv[8];
      #pragma unroll
      for(int q=0;q<4;q++){
        unsigned int wd = (unsigned int)xv[q];
        xsv[2*q]   = bf2f((unsigned short)(wd & 0xffffu));
        xsv[2*q+1] = bf2f((unsigned short)(wd >> 16));
      }
      #pragma unroll
      for(int k=0;k<8;k++) acc[k] += xsv[k]*w4[k][j];
      if (j==3){
        #pragma unroll
        for(int k=0;k<8;k++) xcur[k] = xsv[k];
      }
    }
  }
  if (l >= SEQ-4){
    int b = (int)(m >> 11);
    int jj = l - (SEQ-4);
    #pragma unroll
    for(int k=0;k<8;k++) cs_out[b*16384 + (d0+k)*4 + jj] = xcur[k];
  }
  ivec4 ov;
  #pragma unroll
  for(int q=0;q<4;q++){
    float y0 = acc[2*q]  * sigf(acc[2*q]);
    float y1 = acc[2*q+1]* sigf(acc[2*q+1]);
    ov[q] = (int)((unsigned)f2bf(y0) | ((unsigned)f2bf(y1) << 16));
  }
  *(ivec4*)&ub[m*DINNER + d0] = ov;
}

// ---- exp(dl*a[n]) for a[n] == -(n+1): powers of e1=exp(-dl) ----
__device__ __forceinline__ void exp_powers(float dl, float* e){
  float e1 = __expf(-dl);
  float p2 = e1*e1, p3 = p2*e1, p4 = p2*p2;
  float p5 = p4*e1, p6 = p4*p2, p7 = p4*p3, p8 = p4*p4;
  e[0]=e1; e[1]=p2; e[2]=p3; e[3]=p4; e[4]=p5; e[5]=p6; e[6]=p7; e[7]=p8;
  e[8]=p8*e1; e[9]=p8*p2; e[10]=p8*p3; e[11]=p8*p4;
  e[12]=p8*p5; e[13]=p8*p6; e[14]=p8*p7; e[15]=p8*p8;
}

// ================= chunked parallel scan =================
__global__ __launch_bounds__(256) void scan_part1(
    const unsigned short* __restrict__ delta_b,
    const unsigned short* __restrict__ u_b,
    const float* __restrict__ xdbl,
    const float* __restrict__ Amat,
    float* __restrict__ S,
    float* __restrict__ sdelta)
{
  const int t = threadIdx.x;
  const int blk = blockIdx.x;
  const int c = blk & 15, b = (blk>>4)&3, d = (blk>>6)*256 + t;
  float a[16], s[16];
  #pragma unroll
  for (int n=0;n<16;n++){ a[n] = Amat[n*DINNER+d]; s[n]=0.f; }
  bool powA = true;
  #pragma unroll
  for (int n=0;n<16;n++) powA = powA && (a[n] == -(float)(n+1));
  float sd = 0.f;
  const long mbase = (long)b*SEQ + c*LC;

#define S1_BODY(EXPR_E) \
  for (int l=0;l<LC;l++){ \
    long m = mbase + l; \
    float dl = bf2f(delta_b[m*DINNER+d]); \
    float ul = bf2f(u_b[m*DINNER+d]); \
    const float* xb = &xdbl[m*160 + 128]; \
    float dbu = dl*ul; \
    sd += dl; \
    float e[16]; EXPR_E; \
    _Pragma("unroll") \
    for (int g=0; g<4; g++){ \
      fvec4 Bg = *(const fvec4*)(xb + 4*g); \
      _Pragma("unroll") \
      for (int q=0;q<4;q++){ \
        int n = g*4+q; \
        s[n] = e[n]*s[n] + Bg[q]*dbu; \
      } \
    } \
  }

  if (powA){
    S1_BODY(exp_powers(dl, e))
  } else {
    S1_BODY({ _Pragma("unroll") for (int n=0;n<16;n++) e[n] = __expf(dl*a[n]); })
  }
#undef S1_BODY

  const long base = ((long)(b*NCHUNK + c)*DSTATE)*DINNER + d;
  #pragma unroll
  for (int n=0;n<16;n++) S[base + (long)n*DINNER] = s[n];
  sdelta[(long)(b*NCHUNK+c)*DINNER + d] = sd;
}

__global__ __launch_bounds__(256) void scan_part2(
    const float* __restrict__ S,
    const float* __restrict__ sdelta,
    const float* __restrict__ Amat,
    float* __restrict__ Xin,
    float* __restrict__ last_state)
{
  int id = blockIdx.x*256 + threadIdx.x;
  int d = id & (DINNER-1);
  int n = (id>>12) & 15;
  int b = id>>16;
  float a = Amat[n*DINNER+d];
  float X = 0.f;
  #pragma unroll
  for (int c=0;c<NCHUNK;c++){
    long sb = ((long)(b*NCHUNK+c)*DSTATE + n)*DINNER + d;
    Xin[sb] = X;
    float sd = sdelta[(long)(b*NCHUNK+c)*DINNER + d];
    float Sc = S[sb];
    X = __expf(a*sd)*X + Sc;
  }
  last_state[((long)b*DSTATE + n)*DINNER + d] = X;
}

__global__ __launch_bounds__(256) void scan_part3(
    const unsigned short* __restrict__ delta_b,
    const unsigned short* __restrict__ u_b,
    const unsigned short* __restrict__ z_b,
    const float* __restrict__ xdbl,
    const float* __restrict__ Amat,
    const float* __restrict__ Dvec,
    const float* __restrict__ Xin,
    unsigned short* __restrict__ y_b)
{
  const int t = threadIdx.x;
  const int blk = blockIdx.x;
  const int c = blk & 15, b = (blk>>4)&3, d = (blk>>6)*256 + t;
  float a[16], s[16];
  const long xb0 = ((long)(b*NCHUNK + c)*DSTATE)*DINNER + d;
  #pragma unroll
  for (int n=0;n<16;n++){
    a[n] = Amat[n*DINNER+d];
    s[n] = Xin[xb0 + (long)n*DINNER];
  }
  bool powA = true;
  #pragma unroll
  for (int n=0;n<16;n++) powA = powA && (a[n] == -(float)(n+1));
  const float Dd = Dvec[d];
  const long mbase = (long)b*SEQ + c*LC;

#define S3_BODY(EXPR_E) \
  for (int l=0;l<LC;l++){ \
    long m = mbase + l; \
    float dl = bf2f(delta_b[m*DINNER+d]); \
    float ul = bf2f(u_b[m*DINNER+d]); \
    float zl = bf2f(z_b[m*DINNER+d]); \
    const float* xb = &xdbl[m*160 + 128]; \
    float dbu = dl*ul; \
    float y = 0.f; \
    float e[16]; EXPR_E; \
    _Pragma("unroll") \
    for (int g=0; g<4; g++){ \
      fvec4 Bg = *(const fvec4*)(xb + 4*g); \
      fvec4 Cg = *(const fvec4*)(xb + 16 + 4*g); \
      _Pragma("unroll") \
      for (int q=0;q<4;q++){ \
        int n = g*4+q; \
        s[n] = e[n]*s[n] + Bg[q]*dbu; \
        y += Cg[q]*s[n]; \
      } \
    } \
    float yy = y + ul*Dd; \
    float zs = zl*sigf(zl); \
    y_b[m*DINNER+d] = f2bf(yy*zs); \
  }

  if (powA){
    S3_BODY(exp_powers(dl, e))
  } else {
    S3_BODY({ _Pragma("unroll") for (int n=0;n<16;n++) e[n] = __expf(dl*a[n]); })
  }
#undef S3_BODY
}

// ---------------- launcher ----------------
// Aliased 256 MiB layout:
//   Slot A [0,64M):    hs_b(32M)+w_in_b(32M) -> xpart(21M, step 5-6) ->
//                      delta(64M, step 7+)
//   Slot B [64,128M):  x(64M) -> after conv: wxp@64 wdt@66 wout@68 xdbl@84
//                      dtr@90 S@92(16M) Xin@108(16M) sdelta@124(1M)
//   Slot C [128,192M): z(64M)
//   Slot D [192,256M): u(64M) -> y written in-place by scan_part3
extern "C" void kernel_launch(void* const* d_in, const int* in_sizes, int n_in,
                              void* d_out, int out_size, void* d_ws, size_t ws_size,
                              hipStream_t stream) {
  const float* hs     = (const float*)d_in[0];
  const float* w_in   = (const float*)d_in[6];
  const float* conv_w = (const float*)d_in[7];
  const float* conv_b = (const float*)d_in[8];
  const float* w_xp   = (const float*)d_in[9];
  const float* w_dt   = (const float*)d_in[10];
  const float* dt_bias= (const float*)d_in[11];
  const float* Amat   = (const float*)d_in[12];
  const float* Dvec   = (const float*)d_in[13];
  const float* w_out  = (const float*)d_in[14];
  float* out = (float*)d_out;

  char* ws = (char*)d_ws;
  const size_t MiB = (size_t)1 << 20;

  unsigned short *hs_b, *w_in_b, *x_b, *z_b, *u_b, *delta_b;
  unsigned short *wxp_b, *wdt_b, *wout_b, *dtr_b, *y_b;
  float *xdbl, *Sbuf, *Xin, *sdelta, *xpart;

  if (ws_size >= 424*MiB){
    size_t off = 0;
    auto alloc = [&](size_t bytes)->void*{ void* p = ws + off; off += (bytes + 255) & ~(size_t)255; return p; };
    hs_b   = (unsigned short*)alloc((size_t)MROWS*DMODEL*2);
    w_in_b = (unsigned short*)alloc((size_t)2*DINNER*DMODEL*2);
    x_b    = (unsigned short*)alloc((size_t)MROWS*DINNER*2);
    z_b    = (unsigned short*)alloc((size_t)MROWS*DINNER*2);
    u_b    = (unsigned short*)alloc((size_t)MROWS*DINNER*2);
    delta_b= (unsigned short*)alloc((size_t)MROWS*DINNER*2);
    wxp_b  = (unsigned short*)alloc((size_t)160*DINNER*2);
    wdt_b  = (unsigned short*)alloc((size_t)DINNER*DTRANK*2);
    wout_b = (unsigned short*)alloc((size_t)DMODEL*DINNER*2);
    xdbl   = (float*)alloc((size_t)MROWS*160*4);
    dtr_b  = (unsigned short*)alloc((size_t)MROWS*DTRANK*2);
    Sbuf   = (float*)alloc((size_t)NB*NCHUNK*DSTATE*DINNER*4);
    Xin    = (float*)alloc((size_t)NB*NCHUNK*DSTATE*DINNER*4);
    sdelta = (float*)alloc((size_t)NB*NCHUNK*DINNER*4);
    xpart  = (float*)alloc((size_t)4*MROWS*160*4);
    y_b    = x_b;
  } else {
    hs_b    = (unsigned short*)(ws + 0);
    w_in_b  = (unsigned short*)(ws + 32*MiB);
    xpart   = (float*)         (ws + 0);   // steps 5-6 (hs/w_in dead)
    delta_b = (unsigned short*)(ws + 0);   // step 7+ (xpart dead)
    x_b     = (unsigned short*)(ws + 64*MiB);
    wxp_b   = (unsigned short*)(ws + 64*MiB);
    wdt_b   = (unsigned short*)(ws + 66*MiB);
    wout_b  = (unsigned short*)(ws + 68*MiB);
    xdbl    = (float*)         (ws + 84*MiB);
    dtr_b   = (unsigned short*)(ws + 90*MiB);
    Sbuf    = (float*)         (ws + 92*MiB);
    Xin     = (float*)         (ws + 108*MiB);
    sdelta  = (float*)         (ws + 124*MiB);
    z_b     = (unsigned short*)(ws + 128*MiB);
    u_b     = (unsigned short*)(ws + 192*MiB);
    y_b     = u_b;
  }

  // 1) converts needed for in_proj
  cvt2_kernel<<<(2*MROWS*DMODEL)/1024, 256, 0, stream>>>(hs, hs_b, w_in, w_in_b,
                                                         MROWS*DMODEL);
  // 2) in_proj: 256^2 tiles -> 32x32=1024 blocks (K=2048 -> NKT=32)
  gemm256<0><<<1024, 512, 0, stream>>>(hs_b, w_in_b, DMODEL, 32, 0,
                                       x_b, z_b, nullptr);
  // 3) conv + silu -> u, fused conv_state output (x dead afterwards)
  conv_silu_kernel<<<(MROWS*512)/256, 256, 0, stream>>>(x_b, conv_w, conv_b, u_b,
                                                        out + (size_t)MROWS*DMODEL);
  // 4) weight converts (one kernel, into dead-x slot in aliased mode)
  {
    int na = 160*DINNER, nb = DINNER*DTRANK, nc = DMODEL*DINNER;
    int tot4 = (na+nb+nc)/4;
    cvt3_kernel<<<(tot4+255)/256, 256, 0, stream>>>(w_xp, wxp_b, na,
                                                    w_dt, wdt_b, nb,
                                                    w_out, wout_b, nc);
  }
  // 5) x_proj split-K x4 -> partials
  gemm_bt<4><<<dim3(2,64,4), 256, 0, stream>>>(u_b, wxp_b, DINNER, 1024, 160,
                                               xpart, nullptr, nullptr, 160);
  // 6) reduce partials -> xdbl fp32 + dtr bf16
  reduce_xproj<<<(MROWS*160/4)/256, 256, 0, stream>>>(xpart, xdbl, dtr_b);
  // 7) dt_proj + softplus -> delta (m97-style)
  gemm_bt<2><<<dim3(32,64), 256, 0, stream>>>(dtr_b, wdt_b, DTRANK, DTRANK, DINNER,
                                              nullptr, delta_b, dt_bias, DINNER);
  // 8) chunked scan
  scan_part1<<<1024, 256, 0, stream>>>(delta_b, u_b, xdbl, Amat, Sbuf, sdelta);
  scan_part2<<<1024, 256, 0, stream>>>(Sbuf, sdelta, Amat, Xin,
                                       out + (size_t)MROWS*DMODEL + NB*DINNER*4);
  scan_part3<<<1024, 256, 0, stream>>>(delta_b, u_b, z_b, xdbl, Amat, Dvec, Xin, y_b);
  // 9) out_proj: 32x8=256 blocks (K=4096 -> NKT=64)
  gemm256<3><<<256, 512, 0, stream>>>(y_b, wout_b, DINNER, 8, DMODEL,
                                      nullptr, nullptr, out);
}

// Round 14
// 823.932 us; speedup vs baseline: 1.0618x; 1.0616x over previous
//
#include <hip/hip_runtime.h>
#include <hip/hip_bf16.h>
#include <math.h>

typedef __attribute__((ext_vector_type(4))) float fvec4;
typedef __attribute__((ext_vector_type(4))) int ivec4;
typedef __attribute__((ext_vector_type(4))) unsigned short usvec4;
typedef __attribute__((ext_vector_type(8))) short bf16x8;

#define SEQ 2048
#define DMODEL 2048
#define DINNER 4096
#define DSTATE 16
#define DTRANK 128
#define NB 4
#define MROWS (NB*SEQ)  // 8192
#define NCHUNK 32
#define LC (SEQ/NCHUNK) // 64

__device__ __forceinline__ float bf2f(unsigned short h){
  union{unsigned int u; float f;} v; v.u = ((unsigned int)h)<<16; return v.f;
}
__device__ __forceinline__ unsigned short f2bf(float f){
  union{float f; unsigned int u;} v; v.f=f;
  unsigned int r = v.u + 0x7fffu + ((v.u>>16)&1u);
  return (unsigned short)(r>>16);
}
__device__ __forceinline__ void async16(const void* g, void* l){
  __builtin_amdgcn_global_load_lds((const __attribute__((address_space(1))) void*)g,
                                   (__attribute__((address_space(3))) void*)l, 16, 0, 0);
}
__device__ __forceinline__ float sigf(float x){ return 1.f/(1.f+__expf(-x)); }

__device__ __forceinline__ void cvt4(const float* s, unsigned short* d, int i){
  fvec4 v = *(const fvec4*)(s + i);
  usvec4 o;
  o[0]=f2bf(v[0]); o[1]=f2bf(v[1]); o[2]=f2bf(v[2]); o[3]=f2bf(v[3]);
  *(usvec4*)(d + i) = o;
}

// ---------------- fused fp32 -> bf16 converts ----------------
__global__ void cvt2_kernel(const float* __restrict__ a, unsigned short* __restrict__ oa,
                            const float* __restrict__ b, unsigned short* __restrict__ ob, int n){
  int i = (blockIdx.x*256 + threadIdx.x)*4;
  if (i < n) cvt4(a, oa, i);
  else       cvt4(b, ob, i - n);
}
__global__ void cvt3_kernel(const float* __restrict__ a, unsigned short* __restrict__ oa, int na,
                            const float* __restrict__ b, unsigned short* __restrict__ ob, int nb,
                            const float* __restrict__ c, unsigned short* __restrict__ oc, int nc){
  int i = (blockIdx.x*256 + threadIdx.x)*4;
  if (i < na){ cvt4(a, oa, i); return; }
  i -= na;
  if (i < nb){ cvt4(b, ob, i); return; }
  i -= nb;
  if (i < nc) cvt4(c, oc, i);
}

// ================= 256x256 GEMM (C = A * B^T), BK=64 2-slot =================
// r11 proven config (257us in_proj, MfmaUtil 48%, 0 bank conflicts, VGPR 112).
// The 32x32x16 variant (r12/r13) hit persistent 2.5e7 LDS conflicts under
// both swizzle keys tried — 32-row fragment reads conflict in a way the
// bank model doesn't capture; reverted. DO NOT switch MFMA shape again
// without an asm-level conflict theory.
// One {vmcnt(0); barrier} per K-tile (64 MFMA); reads issued one 16-MFMA
// cluster ahead; swizzle slot = (4k+fc)^(fr&7) both-sides (rule #21).
// (512,2): 256-reg budget ((512,4) spills acc — r5, 9x).
// MODE 0: split x/z bf16 at col 4096 (in_proj). MODE 3: fp32 store (out_proj).
template<int MODE>
__global__ __launch_bounds__(512, 2) void gemm256(
    const unsigned short* __restrict__ A,
    const unsigned short* __restrict__ B,
    int K, int nbx, int ldc,
    unsigned short* __restrict__ Cb1,
    unsigned short* __restrict__ Cb2,
    float* __restrict__ Cf)
{
  __shared__ __align__(16) unsigned short lds[65536];  // 128 KiB: 2 x 64 KiB
  char* ldsc = (char*)lds;
  const int t = threadIdx.x;

  // T1: XCD swizzle (gridDim.x % 8 == 0 for all uses)
  const int nwg = gridDim.x;
  const int cpx = nwg >> 3;
  const int bid = blockIdx.x;
  const int swzb = (bid & 7)*cpx + (bid >> 3);
  const int bx = swzb % nbx, by = swzb / nbx;

  // staging (per slot: A[256][64] bf16 @0 (32KB, 128B rows), B @32768).
  const int r0 = t>>3;
  const int cel = ((t&7) ^ (r0&7)) * 8;
  const unsigned short* gA = A + (long)by*256*K + (long)r0*K + cel;
  const unsigned short* gB = B + (long)bx*256*K + (long)r0*K + cel;
  const long P64 = 64L*K;

  // fragment read offsets: x0 = ksub0 swizzled col bytes, x1 = ksub1
  const int wid = t>>6, lane = t&63;
  const int wm = wid>>2, wn = wid&3;
  const int fr = lane&15, fc = lane>>4;
  const int x0 = ((fc ^ (fr&7))<<4);
  const int x1 = (((4+fc) ^ (fr&7))<<4);
  const int arow = (wm*128 + fr)*128;          // + i*2048
  const int brow = 32768 + (wn*64 + fr)*128;   // + j*2048

  fvec4 acc[8][4];
  #pragma unroll
  for (int i=0;i<8;i++){
    #pragma unroll
    for (int j=0;j<4;j++) acc[i][j] = (fvec4)(0.f);
  }

  const int NKT = K >> 6;
  auto stage = [&](int slot, int k0){
    char* sb = ldsc + slot*65536;
    #pragma unroll
    for (int p=0;p<4;p++) async16(gA + p*P64 + k0, sb + p*8192 + t*16);
    #pragma unroll
    for (int p=0;p<4;p++) async16(gB + p*P64 + k0, sb + 32768 + p*8192 + t*16);
  };

  stage(0, 0);   // prologue: tile 0 into slot 0

  bf16x8 aP[4], aQ[4], bU[4], bV[4];
  for (int kt = 0; kt < NKT; ++kt){
    const char* cs = ldsc + (kt&1)*65536;
    asm volatile("s_waitcnt vmcnt(0)" ::: "memory");  // tile kt staged (only kt's 8 outstanding)
    __builtin_amdgcn_s_barrier();                     // staged chip-wide; other slot's readers done
    __builtin_amdgcn_sched_barrier(0);
    if (kt+1 < NKT) stage((kt+1)&1, (kt+1)*64);       // prefetch next tile
    __builtin_amdgcn_sched_barrier(0);
    // C1 operands + C2 read-ahead
    #pragma unroll
    for (int i=0;i<4;i++) aP[i] = *(const bf16x8*)(cs + arow + i*2048 + x0);
    #pragma unroll
    for (int j=0;j<4;j++) bU[j] = *(const bf16x8*)(cs + brow + j*2048 + x0);
    #pragma unroll
    for (int i=0;i<4;i++) aQ[i] = *(const bf16x8*)(cs + arow + (4+i)*2048 + x0);
    __builtin_amdgcn_s_setprio(1);
    #pragma unroll
    for (int i=0;i<4;i++){
      #pragma unroll
      for (int j=0;j<4;j++)
        acc[i][j] = __builtin_amdgcn_mfma_f32_16x16x32_bf16(aP[i], bU[j], acc[i][j], 0,0,0);
    }
    __builtin_amdgcn_s_setprio(0);
    // C3 read-ahead (ksub1), then C2 MFMA
    #pragma unroll
    for (int i=0;i<4;i++) aP[i] = *(const bf16x8*)(cs + arow + i*2048 + x1);
    #pragma unroll
    for (int j=0;j<4;j++) bV[j] = *(const bf16x8*)(cs + brow + j*2048 + x1);
    __builtin_amdgcn_s_setprio(1);
    #pragma unroll
    for (int i=0;i<4;i++){
      #pragma unroll
      for (int j=0;j<4;j++)
        acc[4+i][j] = __builtin_amdgcn_mfma_f32_16x16x32_bf16(aQ[i], bU[j], acc[4+i][j], 0,0,0);
    }
    __builtin_amdgcn_s_setprio(0);
    // C4 read-ahead, then C3 MFMA
    #pragma unroll
    for (int i=0;i<4;i++) aQ[i] = *(const bf16x8*)(cs + arow + (4+i)*2048 + x1);
    __builtin_amdgcn_s_setprio(1);
    #pragma unroll
    for (int i=0;i<4;i++){
      #pragma unroll
      for (int j=0;j<4;j++)
        acc[i][j] = __builtin_amdgcn_mfma_f32_16x16x32_bf16(aP[i], bV[j], acc[i][j], 0,0,0);
    }
    // C4 MFMA
    #pragma unroll
    for (int i=0;i<4;i++){
      #pragma unroll
      for (int j=0;j<4;j++)
        acc[4+i][j] = __builtin_amdgcn_mfma_f32_16x16x32_bf16(aQ[i], bV[j], acc[4+i][j], 0,0,0);
    }
    __builtin_amdgcn_s_setprio(0);
  }

  const long crow0 = (long)by*256 + wm*128;
  const int  ccol0 = bx*256 + wn*64;
  #pragma unroll
  for (int i=0;i<8;i++){
    #pragma unroll
    for (int j=0;j<4;j++){
      #pragma unroll
      for (int q=0;q<4;q++){
        long rg = crow0 + i*16 + fc*4 + q;
        int  cg = ccol0 + j*16 + fr;
        float v = acc[i][j][q];
        if (MODE==0){
          if (cg < DINNER) Cb1[rg*DINNER + cg] = f2bf(v);
          else             Cb2[rg*DINNER + (cg-DINNER)] = f2bf(v);
        } else {
          Cf[rg*(long)ldc + cg] = v;
        }
      }
    }
  }
}

// ---------------- m97-style 128x128 GEMM for the small projections ----------------
// MODE 2: softplus(v+bias) -> bf16 (dt_proj -> delta)
// MODE 4: split-K partial fp32 store (x_proj), z = blockIdx.z K-slice
template<int MODE>
__global__ __launch_bounds__(256) void gemm_bt(
    const unsigned short* __restrict__ A,
    const unsigned short* __restrict__ B,
    int lda, int Kloop, int Nreal,
    float* __restrict__ Cf,
    unsigned short* __restrict__ Cb1,
    const float* __restrict__ bias,
    int ldc)
{
  __shared__ __align__(16) unsigned short As[128*32];
  __shared__ __align__(16) unsigned short Bs[128*32];
  const int t = threadIdx.x;
  const int bx = blockIdx.x, by = blockIdx.y;
  const long koff = (MODE==4) ? (long)blockIdx.z * Kloop : 0;
  const int wave = t>>6, lane = t&63;
  const int wr = (wave>>1)*64, wc = (wave&1)*64;
  const int fr = lane&15, fc = lane>>4;
  fvec4 acc[4][4];
  #pragma unroll
  for(int i=0;i<4;i++){
    #pragma unroll
    for(int j=0;j<4;j++){ acc[i][j] = (fvec4)(0.f); }
  }
  const int srow = t>>2;
  const int scol = (t&3)*8;
  long rowA = (long)by*128 + srow;
  int rB0 = bx*128 + srow;      if (rB0 > Nreal-1) rB0 = Nreal-1;
  int rB1 = bx*128 + 64 + srow; if (rB1 > Nreal-1) rB1 = Nreal-1;
  const unsigned short* gA0 = A + rowA*(long)lda + scol + koff;
  const unsigned short* gA1 = gA0 + 64L*lda;
  const unsigned short* gB0 = B + (long)rB0*lda + scol + koff;
  const unsigned short* gB1 = B + (long)rB1*lda + scol + koff;
  unsigned short* lA0 = &As[t*8];
  unsigned short* lA1 = &As[2048 + t*8];
  unsigned short* lB0 = &Bs[t*8];
  unsigned short* lB1 = &Bs[2048 + t*8];

  for (int k0 = 0; k0 < Kloop; k0 += 32){
    async16(gA0 + k0, lA0);
    async16(gA1 + k0, lA1);
    async16(gB0 + k0, lB0);
    async16(gB1 + k0, lB1);
    __syncthreads();
    bf16x8 af[4], bv[4];
    #pragma unroll
    for(int i=0;i<4;i++){
      af[i] = *(const bf16x8*)&As[(wr + i*16 + fr)*32 + fc*8];
      bv[i] = *(const bf16x8*)&Bs[(wc + i*16 + fr)*32 + fc*8];
    }
    #pragma unroll
    for(int i=0;i<4;i++){
      #pragma unroll
      for(int j=0;j<4;j++){
        acc[i][j] = __builtin_amdgcn_mfma_f32_16x16x32_bf16(af[i], bv[j], acc[i][j], 0,0,0);
      }
    }
    __syncthreads();
  }

  const long crow0 = (long)by*128 + wr;
  const int ccol0 = bx*128 + wc;
  float* Cfz = (MODE==4) ? (Cf + (long)blockIdx.z * MROWS * ldc) : Cf;
  #pragma unroll
  for(int i=0;i<4;i++){
    #pragma unroll
    for(int j=0;j<4;j++){
      #pragma unroll
      for(int q=0;q<4;q++){
        long rg = crow0 + i*16 + fc*4 + q;
        int  cg = ccol0 + j*16 + fr;
        float v = acc[i][j][q];
        if (MODE==4){
          if (cg < Nreal) Cfz[rg*ldc + cg] = v;
        } else if (MODE==2){
          float x = v + bias[cg];
          float sp = (x > 20.f) ? x : log1pf(__expf(x));
          Cb1[rg*ldc + cg] = f2bf(sp);
        }
      }
    }
  }
}

// ---------------- reduce x_proj partials + emit dtr bf16 ----------------
__global__ void reduce_xproj(const float* __restrict__ part,
                             float* __restrict__ xdbl,
                             unsigned short* __restrict__ dtr){
  int i = blockIdx.x*256 + threadIdx.x;           // x4 elems, 8192*160/4 total
  long base = (long)i*4;
  fvec4 s = *(const fvec4*)&part[base];
  #pragma unroll
  for (int z=1; z<4; z++){
    fvec4 p = *(const fvec4*)&part[(long)z*MROWS*160 + base];
    s[0]+=p[0]; s[1]+=p[1]; s[2]+=p[2]; s[3]+=p[3];
  }
  *(fvec4*)&xdbl[base] = s;
  long mrow = base / 160;
  int c = (int)(base - mrow*160);
  if (c < DTRANK){
    usvec4 o; o[0]=f2bf(s[0]); o[1]=f2bf(s[1]); o[2]=f2bf(s[2]); o[3]=f2bf(s[3]);
    *(usvec4*)&dtr[mrow*DTRANK + c] = o;
  }
}

// ------- depthwise causal conv(4) + bias + SiLU (+ fused conv_state) -------
__global__ __launch_bounds__(256) void conv_silu_kernel(
    const unsigned short* __restrict__ xb, const float* __restrict__ w,
    const float* __restrict__ bias, unsigned short* __restrict__ ub,
    float* __restrict__ cs_out)
{
  int gid = blockIdx.x*256 + threadIdx.x;
  int d0 = (gid & 511)*8;
  long m = gid >> 9;
  int l = (int)(m & (SEQ-1));
  fvec4 w4[8];
  #pragma unroll
  for(int k=0;k<8;k++) w4[k] = *(const fvec4*)&w[(d0+k)*4];
  float acc[8];
  fvec4 b0 = *(const fvec4*)&bias[d0];
  fvec4 b1 = *(const fvec4*)&bias[d0+4];
  acc[0]=b0[0];acc[1]=b0[1];acc[2]=b0[2];acc[3]=b0[3];
  acc[4]=b1[0];acc[5]=b1[1];acc[6]=b1[2];acc[7]=b1[3];
  float xcur[8];
  #pragma unroll
  for(int j=0;j<4;j++){
    int lj = l-3+j;
    if (lj >= 0){
      ivec4 xv = *(const ivec4*)&xb[(m-3+j)*DINNER + d0];
      float xsv[8];
      #pragma unroll
      for(int q=0;q<4;q++){
        unsigned int wd = (unsigned int)xv[q];
        xsv[2*q]   = bf2f((unsigned short)(wd & 0xffffu));
        xsv[2*q+1] = bf2f((unsigned short)(wd >> 16));
      }
      #pragma unroll
      for(int k=0;k<8;k++) acc[k] += xsv[k]*w4[k][j];
      if (j==3){
        #pragma unroll
        for(int k=0;k<8;k++) xcur[k] = xsv[k];
      }
    }
  }
  if (l >= SEQ-4){
    int b = (int)(m >> 11);
    int jj = l - (SEQ-4);
    #pragma unroll
    for(int k=0;k<8;k++) cs_out[b*16384 + (d0+k)*4 + jj] = xcur[k];
  }
  ivec4 ov;
  #pragma unroll
  for(int q=0;q<4;q++){
    float y0 = acc[2*q]  * sigf(acc[2*q]);
    float y1 = acc[2*q+1]* sigf(acc[2*q+1]);
    ov[q] = (int)((unsigned)f2bf(y0) | ((unsigned)f2bf(y1) << 16));
  }
  *(ivec4*)&ub[m*DINNER + d0] = ov;
}

// ---- exp(dl*a[n]) for a[n] == -(n+1): powers of e1=exp(-dl) ----
__device__ __forceinline__ void exp_powers(float dl, float* e){
  float e1 = __expf(-dl);
  float p2 = e1*e1, p3 = p2*e1, p4 = p2*p2;
  float p5 = p4*e1, p6 = p4*p2, p7 = p4*p3, p8 = p4*p4;
  e[0]=e1; e[1]=p2; e[2]=p3; e[3]=p4; e[4]=p5; e[5]=p6; e[6]=p7; e[7]=p8;
  e[8]=p8*e1; e[9]=p8*p2; e[10]=p8*p3; e[11]=p8*p4;
  e[12]=p8*p5; e[13]=p8*p6; e[14]=p8*p7; e[15]=p8*p8;
}

// ================= chunked parallel scan (NCHUNK=32, LC=64) =================
// scan1/scan3: 2048 blocks -> 8 blocks/CU (was 4) for better latency hiding.
__global__ __launch_bounds__(256) void scan_part1(
    const unsigned short* __restrict__ delta_b,
    const unsigned short* __restrict__ u_b,
    const float* __restrict__ xdbl,
    const float* __restrict__ Amat,
    float* __restrict__ S,
    float* __restrict__ sdelta)
{
  const int t = threadIdx.x;
  const int blk = blockIdx.x;
  const int c = blk & (NCHUNK-1), b = (blk>>5)&3, d = (blk>>7)*256 + t;
  float a[16], s[16];
  #pragma unroll
  for (int n=0;n<16;n++){ a[n] = Amat[n*DINNER+d]; s[n]=0.f; }
  bool powA = true;
  #pragma unroll
  for (int n=0;n<16;n++) powA = powA && (a[n] == -(float)(n+1));
  float sd = 0.f;
  const long mbase = (long)b*SEQ + c*LC;

#define S1_BODY(EXPR_E) \
  for (int l=0;l<LC;l++){ \
    long m = mbase + l; \
    float dl = bf2f(delta_b[m*DINNER+d]); \
    float ul = bf2f(u_b[m*DINNER+d]); \
    const float* xb = &xdbl[m*160 + 128]; \
    float dbu = dl*ul; \
    sd += dl; \
    float e[16]; EXPR_E; \
    _Pragma("unroll") \
    for (int g=0; g<4; g++){ \
      fvec4 Bg = *(const fvec4*)(xb + 4*g); \
      _Pragma("unroll") \
      for (int q=0;q<4;q++){ \
        int n = g*4+q; \
        s[n] = e[n]*s[n] + Bg[q]*dbu; \
      } \
    } \
  }

  if (powA){
    S1_BODY(exp_powers(dl, e))
  } else {
    S1_BODY({ _Pragma("unroll") for (int n=0;n<16;n++) e[n] = __expf(dl*a[n]); })
  }
#undef S1_BODY

  const long base = ((long)(b*NCHUNK + c)*DSTATE)*DINNER + d;
  #pragma unroll
  for (int n=0;n<16;n++) S[base + (long)n*DINNER] = s[n];
  sdelta[(long)(b*NCHUNK+c)*DINNER + d] = sd;
}

// part2: IN-PLACE over SX (S on input, Xin on output — same buffer, single
// non-restrict pointer so the per-element load precedes the store).
__global__ __launch_bounds__(256) void scan_part2(
    float* SX,
    const float* __restrict__ sdelta,
    const float* __restrict__ Amat,
    float* __restrict__ last_state)
{
  int id = blockIdx.x*256 + threadIdx.x;
  int d = id & (DINNER-1);
  int n = (id>>12) & 15;
  int b = id>>16;
  float a = Amat[n*DINNER+d];
  float X = 0.f;
  #pragma unroll
  for (int c=0;c<NCHUNK;c++){
    long sb = ((long)(b*NCHUNK+c)*DSTATE + n)*DINNER + d;
    float Sc = SX[sb];
    float sd = sdelta[(long)(b*NCHUNK+c)*DINNER + d];
    SX[sb] = X;                      // entering state for chunk c
    X = __expf(a*sd)*X + Sc;
  }
  last_state[((long)b*DSTATE + n)*DINNER + d] = X;
}

__global__ __launch_bounds__(256) void scan_part3(
    const unsigned short* __restrict__ delta_b,
    const unsigned short* __restrict__ u_b,
    const unsigned short* __restrict__ z_b,
    const float* __restrict__ xdbl,
    const float* __restrict__ Amat,
    const float* __restrict__ Dvec,
    const float* __restrict__ Xin,
    unsigned short* __restrict__ y_b)
{
  const int t = threadIdx.x;
  const int blk = blockIdx.x;
  const int c = blk & (NCHUNK-1), b = (blk>>5)&3, d = (blk>>7)*256 + t;
  float a[16], s[16];
  const long xb0 = ((long)(b*NCHUNK + c)*DSTATE)*DINNER + d;
  #pragma unroll
  for (int n=0;n<16;n++){
    a[n] = Amat[n*DINNER+d];
    s[n] = Xin[xb0 + (long)n*DINNER];
  }
  bool powA = true;
  #pragma unroll
  for (int n=0;n<16;n++) powA = powA && (a[n] == -(float)(n+1));
  const float Dd = Dvec[d];
  const long mbase = (long)b*SEQ + c*LC;

#define S3_BODY(EXPR_E) \
  for (int l=0;l<LC;l++){ \
    long m = mbase + l; \
    float dl = bf2f(delta_b[m*DINNER+d]); \
    float ul = bf2f(u_b[m*DINNER+d]); \
    float zl = bf2f(z_b[m*DINNER+d]); \
    const float* xb = &xdbl[m*160 + 128]; \
    float dbu = dl*ul; \
    float y = 0.f; \
    float e[16]; EXPR_E; \
    _Pragma("unroll") \
    for (int g=0; g<4; g++){ \
      fvec4 Bg = *(const fvec4*)(xb + 4*g); \
      fvec4 Cg = *(const fvec4*)(xb + 16 + 4*g); \
      _Pragma("unroll") \
      for (int q=0;q<4;q++){ \
        int n = g*4+q; \
        s[n] = e[n]*s[n] + Bg[q]*dbu; \
        y += Cg[q]*s[n]; \
      } \
    } \
    float yy = y + ul*Dd; \
    float zs = zl*sigf(zl); \
    y_b[m*DINNER+d] = f2bf(yy*zs); \
  }

  if (powA){
    S3_BODY(exp_powers(dl, e))
  } else {
    S3_BODY({ _Pragma("unroll") for (int n=0;n<16;n++) e[n] = __expf(dl*a[n]); })
  }
#undef S3_BODY
}

// ---------------- launcher ----------------
// Aliased 256 MiB layout:
//   Slot A [0,64M):    hs_b(32M)+w_in_b(32M) -> xpart(21M, step 5-6) ->
//                      delta(64M, step 7+)
//   Slot B [64,128M):  x(64M) -> after conv: wxp@64 wdt@66 wout@68 xdbl@84
//                      dtr@90 SX@92(32M, S then Xin in-place) sdelta@124(2M)
//   Slot C [128,192M): z(64M)
//   Slot D [192,256M): u(64M) -> y written in-place by scan_part3
extern "C" void kernel_launch(void* const* d_in, const int* in_sizes, int n_in,
                              void* d_out, int out_size, void* d_ws, size_t ws_size,
                              hipStream_t stream) {
  const float* hs     = (const float*)d_in[0];
  const float* w_in   = (const float*)d_in[6];
  const float* conv_w = (const float*)d_in[7];
  const float* conv_b = (const float*)d_in[8];
  const float* w_xp   = (const float*)d_in[9];
  const float* w_dt   = (const float*)d_in[10];
  const float* dt_bias= (const float*)d_in[11];
  const float* Amat   = (const float*)d_in[12];
  const float* Dvec   = (const float*)d_in[13];
  const float* w_out  = (const float*)d_in[14];
  float* out = (float*)d_out;

  char* ws = (char*)d_ws;
  const size_t MiB = (size_t)1 << 20;

  unsigned short *hs_b, *w_in_b, *x_b, *z_b, *u_b, *delta_b;
  unsigned short *wxp_b, *wdt_b, *wout_b, *dtr_b, *y_b;
  float *xdbl, *SX, *sdelta, *xpart;

  if (ws_size >= 424*MiB){
    size_t off = 0;
    auto alloc = [&](size_t bytes)->void*{ void* p = ws + off; off += (bytes + 255) & ~(size_t)255; return p; };
    hs_b   = (unsigned short*)alloc((size_t)MROWS*DMODEL*2);
    w_in_b = (unsigned short*)alloc((size_t)2*DINNER*DMODEL*2);
    x_b    = (unsigned short*)alloc((size_t)MROWS*DINNER*2);
    z_b    = (unsigned short*)alloc((size_t)MROWS*DINNER*2);
    u_b    = (unsigned short*)alloc((size_t)MROWS*DINNER*2);
    delta_b= (unsigned short*)alloc((size_t)MROWS*DINNER*2);
    wxp_b  = (unsigned short*)alloc((size_t)160*DINNER*2);
    wdt_b  = (unsigned short*)alloc((size_t)DINNER*DTRANK*2);
    wout_b = (unsigned short*)alloc((size_t)DMODEL*DINNER*2);
    xdbl   = (float*)alloc((size_t)MROWS*160*4);
    dtr_b  = (unsigned short*)alloc((size_t)MROWS*DTRANK*2);
    SX     = (float*)alloc((size_t)NB*NCHUNK*DSTATE*DINNER*4);
    sdelta = (float*)alloc((size_t)NB*NCHUNK*DINNER*4);
    xpart  = (float*)alloc((size_t)4*MROWS*160*4);
    y_b    = x_b;
  } else {
    hs_b    = (unsigned short*)(ws + 0);
    w_in_b  = (unsigned short*)(ws + 32*MiB);
    xpart   = (float*)         (ws + 0);   // steps 5-6 (hs/w_in dead)
    delta_b = (unsigned short*)(ws + 0);   // step 7+ (xpart dead)
    x_b     = (unsigned short*)(ws + 64*MiB);
    wxp_b   = (unsigned short*)(ws + 64*MiB);
    wdt_b   = (unsigned short*)(ws + 66*MiB);
    wout_b  = (unsigned short*)(ws + 68*MiB);
    xdbl    = (float*)         (ws + 84*MiB);
    dtr_b   = (unsigned short*)(ws + 90*MiB);
    SX      = (float*)         (ws + 92*MiB);   // 32 MiB: 92..124
    sdelta  = (float*)         (ws + 124*MiB);  //  2 MiB: 124..126
    z_b     = (unsigned short*)(ws + 128*MiB);
    u_b     = (unsigned short*)(ws + 192*MiB);
    y_b     = u_b;
  }

  // 1) converts needed for in_proj
  cvt2_kernel<<<(2*MROWS*DMODEL)/1024, 256, 0, stream>>>(hs, hs_b, w_in, w_in_b,
                                                         MROWS*DMODEL);
  // 2) in_proj: 256^2 tiles -> 32x32=1024 blocks (K=2048 -> NKT=32)
  gemm256<0><<<1024, 512, 0, stream>>>(hs_b, w_in_b, DMODEL, 32, 0,
                                       x_b, z_b, nullptr);
  // 3) conv + silu -> u, fused conv_state output (x dead afterwards)
  conv_silu_kernel<<<(MROWS*512)/256, 256, 0, stream>>>(x_b, conv_w, conv_b, u_b,
                                                        out + (size_t)MROWS*DMODEL);
  // 4) weight converts (one kernel, into dead-x slot in aliased mode)
  {
    int na = 160*DINNER, nb = DINNER*DTRANK, nc = DMODEL*DINNER;
    int tot4 = (na+nb+nc)/4;
    cvt3_kernel<<<(tot4+255)/256, 256, 0, stream>>>(w_xp, wxp_b, na,
                                                    w_dt, wdt_b, nb,
                                                    w_out, wout_b, nc);
  }
  // 5) x_proj split-K x4 -> partials
  gemm_bt<4><<<dim3(2,64,4), 256, 0, stream>>>(u_b, wxp_b, DINNER, 1024, 160,
                                               xpart, nullptr, nullptr, 160);
  // 6) reduce partials -> xdbl fp32 + dtr bf16
  reduce_xproj<<<(MROWS*160/4)/256, 256, 0, stream>>>(xpart, xdbl, dtr_b);
  // 7) dt_proj + softplus -> delta (m97-style)
  gemm_bt<2><<<dim3(32,64), 256, 0, stream>>>(dtr_b, wdt_b, DTRANK, DTRANK, DINNER,
                                              nullptr, delta_b, dt_bias, DINNER);
  // 8) chunked scan (NCHUNK=32 -> 2048 blocks for part1/part3)
  scan_part1<<<2048, 256, 0, stream>>>(delta_b, u_b, xdbl, Amat, SX, sdelta);
  scan_part2<<<1024, 256, 0, stream>>>(SX, sdelta, Amat,
                                       out + (size_t)MROWS*DMODEL + NB*DINNER*4);
  scan_part3<<<2048, 256, 0, stream>>>(delta_b, u_b, z_b, xdbl, Amat, Dvec, SX, y_b);
  // 9) out_proj: 32x8=256 blocks (K=4096 -> NKT=64)
  gemm256<3><<<256, 512, 0, stream>>>(y_b, wout_b, DINNER, 8, DMODEL,
                                      nullptr, nullptr, out);
}

// Round 15
// 823.619 us; speedup vs baseline: 1.0622x; 1.0004x over previous
//
#include <hip/hip_runtime.h>
#include <hip/hip_bf16.h>
#include <math.h>

typedef __attribute__((ext_vector_type(4))) float fvec4;
typedef __attribute__((ext_vector_type(4))) int ivec4;
typedef __attribute__((ext_vector_type(4))) unsigned short usvec4;
typedef __attribute__((ext_vector_type(8))) short bf16x8;

#define SEQ 2048
#define DMODEL 2048
#define DINNER 4096
#define DSTATE 16
#define DTRANK 128
#define NB 4
#define MROWS (NB*SEQ)  // 8192
#define NCHUNK 32
#define LC (SEQ/NCHUNK) // 64

__device__ __forceinline__ float bf2f(unsigned short h){
  union{unsigned int u; float f;} v; v.u = ((unsigned int)h)<<16; return v.f;
}
__device__ __forceinline__ unsigned short f2bf(float f){
  union{float f; unsigned int u;} v; v.f=f;
  unsigned int r = v.u + 0x7fffu + ((v.u>>16)&1u);
  return (unsigned short)(r>>16);
}
__device__ __forceinline__ void async16(const void* g, void* l){
  __builtin_amdgcn_global_load_lds((const __attribute__((address_space(1))) void*)g,
                                   (__attribute__((address_space(3))) void*)l, 16, 0, 0);
}
__device__ __forceinline__ float sigf(float x){ return 1.f/(1.f+__expf(-x)); }

__device__ __forceinline__ void cvt4(const float* s, unsigned short* d, int i){
  fvec4 v = *(const fvec4*)(s + i);
  usvec4 o;
  o[0]=f2bf(v[0]); o[1]=f2bf(v[1]); o[2]=f2bf(v[2]); o[3]=f2bf(v[3]);
  *(usvec4*)(d + i) = o;
}

// ---------------- fused fp32 -> bf16 converts ----------------
__global__ void cvt2_kernel(const float* __restrict__ a, unsigned short* __restrict__ oa,
                            const float* __restrict__ b, unsigned short* __restrict__ ob, int n){
  int i = (blockIdx.x*256 + threadIdx.x)*4;
  if (i < n) cvt4(a, oa, i);
  else       cvt4(b, ob, i - n);
}
__global__ void cvt3_kernel(const float* __restrict__ a, unsigned short* __restrict__ oa, int na,
                            const float* __restrict__ b, unsigned short* __restrict__ ob, int nb,
                            const float* __restrict__ c, unsigned short* __restrict__ oc, int nc){
  int i = (blockIdx.x*256 + threadIdx.x)*4;
  if (i < na){ cvt4(a, oa, i); return; }
  i -= na;
  if (i < nb){ cvt4(b, ob, i); return; }
  i -= nb;
  if (i < nc) cvt4(c, oc, i);
}

// ================= 256x256 GEMM (C = A * B^T), BK=64 2-slot =================
// FROZEN at r11 config (257us in_proj, MfmaUtil 48%, 0 bank conflicts).
// LDS-read (192KB/tile) and MFMA (2520cy/SIMD) pipes are near-balanced at
// this wave-tile shape — 6 schedule variants (r8-r13) all pinned at 47-48%.
// 32x32x16 MFMA variant conflicts (2.5e7) under every swizzle tried; do not
// revisit without an asm-level theory.
// MODE 0: split x/z bf16 at col 4096 (in_proj). MODE 3: fp32 store (out_proj).
template<int MODE>
__global__ __launch_bounds__(512, 2) void gemm256(
    const unsigned short* __restrict__ A,
    const unsigned short* __restrict__ B,
    int K, int nbx, int ldc,
    unsigned short* __restrict__ Cb1,
    unsigned short* __restrict__ Cb2,
    float* __restrict__ Cf)
{
  __shared__ __align__(16) unsigned short lds[65536];  // 128 KiB: 2 x 64 KiB
  char* ldsc = (char*)lds;
  const int t = threadIdx.x;

  const int nwg = gridDim.x;
  const int cpx = nwg >> 3;
  const int bid = blockIdx.x;
  const int swzb = (bid & 7)*cpx + (bid >> 3);
  const int bx = swzb % nbx, by = swzb / nbx;

  const int r0 = t>>3;
  const int cel = ((t&7) ^ (r0&7)) * 8;
  const unsigned short* gA = A + (long)by*256*K + (long)r0*K + cel;
  const unsigned short* gB = B + (long)bx*256*K + (long)r0*K + cel;
  const long P64 = 64L*K;

  const int wid = t>>6, lane = t&63;
  const int wm = wid>>2, wn = wid&3;
  const int fr = lane&15, fc = lane>>4;
  const int x0 = ((fc ^ (fr&7))<<4);
  const int x1 = (((4+fc) ^ (fr&7))<<4);
  const int arow = (wm*128 + fr)*128;          // + i*2048
  const int brow = 32768 + (wn*64 + fr)*128;   // + j*2048

  fvec4 acc[8][4];
  #pragma unroll
  for (int i=0;i<8;i++){
    #pragma unroll
    for (int j=0;j<4;j++) acc[i][j] = (fvec4)(0.f);
  }

  const int NKT = K >> 6;
  auto stage = [&](int slot, int k0){
    char* sb = ldsc + slot*65536;
    #pragma unroll
    for (int p=0;p<4;p++) async16(gA + p*P64 + k0, sb + p*8192 + t*16);
    #pragma unroll
    for (int p=0;p<4;p++) async16(gB + p*P64 + k0, sb + 32768 + p*8192 + t*16);
  };

  stage(0, 0);

  bf16x8 aP[4], aQ[4], bU[4], bV[4];
  for (int kt = 0; kt < NKT; ++kt){
    const char* cs = ldsc + (kt&1)*65536;
    asm volatile("s_waitcnt vmcnt(0)" ::: "memory");
    __builtin_amdgcn_s_barrier();
    __builtin_amdgcn_sched_barrier(0);
    if (kt+1 < NKT) stage((kt+1)&1, (kt+1)*64);
    __builtin_amdgcn_sched_barrier(0);
    #pragma unroll
    for (int i=0;i<4;i++) aP[i] = *(const bf16x8*)(cs + arow + i*2048 + x0);
    #pragma unroll
    for (int j=0;j<4;j++) bU[j] = *(const bf16x8*)(cs + brow + j*2048 + x0);
    #pragma unroll
    for (int i=0;i<4;i++) aQ[i] = *(const bf16x8*)(cs + arow + (4+i)*2048 + x0);
    __builtin_amdgcn_s_setprio(1);
    #pragma unroll
    for (int i=0;i<4;i++){
      #pragma unroll
      for (int j=0;j<4;j++)
        acc[i][j] = __builtin_amdgcn_mfma_f32_16x16x32_bf16(aP[i], bU[j], acc[i][j], 0,0,0);
    }
    __builtin_amdgcn_s_setprio(0);
    #pragma unroll
    for (int i=0;i<4;i++) aP[i] = *(const bf16x8*)(cs + arow + i*2048 + x1);
    #pragma unroll
    for (int j=0;j<4;j++) bV[j] = *(const bf16x8*)(cs + brow + j*2048 + x1);
    __builtin_amdgcn_s_setprio(1);
    #pragma unroll
    for (int i=0;i<4;i++){
      #pragma unroll
      for (int j=0;j<4;j++)
        acc[4+i][j] = __builtin_amdgcn_mfma_f32_16x16x32_bf16(aQ[i], bU[j], acc[4+i][j], 0,0,0);
    }
    __builtin_amdgcn_s_setprio(0);
    #pragma unroll
    for (int i=0;i<4;i++) aQ[i] = *(const bf16x8*)(cs + arow + (4+i)*2048 + x1);
    __builtin_amdgcn_s_setprio(1);
    #pragma unroll
    for (int i=0;i<4;i++){
      #pragma unroll
      for (int j=0;j<4;j++)
        acc[i][j] = __builtin_amdgcn_mfma_f32_16x16x32_bf16(aP[i], bV[j], acc[i][j], 0,0,0);
    }
    #pragma unroll
    for (int i=0;i<4;i++){
      #pragma unroll
      for (int j=0;j<4;j++)
        acc[4+i][j] = __builtin_amdgcn_mfma_f32_16x16x32_bf16(aQ[i], bV[j], acc[4+i][j], 0,0,0);
    }
    __builtin_amdgcn_s_setprio(0);
  }

  const long crow0 = (long)by*256 + wm*128;
  const int  ccol0 = bx*256 + wn*64;
  #pragma unroll
  for (int i=0;i<8;i++){
    #pragma unroll
    for (int j=0;j<4;j++){
      #pragma unroll
      for (int q=0;q<4;q++){
        long rg = crow0 + i*16 + fc*4 + q;
        int  cg = ccol0 + j*16 + fr;
        float v = acc[i][j][q];
        if (MODE==0){
          if (cg < DINNER) Cb1[rg*DINNER + cg] = f2bf(v);
          else             Cb2[rg*DINNER + (cg-DINNER)] = f2bf(v);
        } else {
          Cf[rg*(long)ldc + cg] = v;
        }
      }
    }
  }
}

// ======= dt_proj: single-stage K=128 GEMM, softplus epilogue =======
// 128x128 tile, 256 thr (4 waves 2x2, wave tile 64x64). Both operands staged
// ONCE (16 gload_lds), one vmcnt(0)+barrier, then 4 ksubs x 16 MFMA.
// LDS rows 256B = 16 16B-slots; frag read slot (4s+fc) XOR fr covers all 16
// slots across the 16 fr rows (conflict-free); same involution pre-applied
// to the staging source (both-sides rule). 64KB LDS -> 2 blocks/CU.
__global__ __launch_bounds__(256) void dt128_kernel(
    const unsigned short* __restrict__ A,   // dtr (8192 x 128)
    const unsigned short* __restrict__ B,   // wdt (4096 x 128)
    const float* __restrict__ bias,
    unsigned short* __restrict__ Cb)        // delta (8192 x 4096)
{
  __shared__ __align__(16) unsigned short lds[32768];  // 64 KiB: A@0, B@32768
  char* ldsc = (char*)lds;
  const int t = threadIdx.x;
  const int bx = blockIdx.x, by = blockIdx.y;

  // staging: pass p covers rows p*16 + (t>>4); dest slot t&15 holds global
  // chunk (t&15)^(r&15)  (source pre-swizzled).
  const int r = t>>4;
  const int cel = ((t&15) ^ (r&15)) * 8;
  const unsigned short* gA = A + ((long)by*128 + r)*DTRANK + cel;
  const unsigned short* gB = B + ((long)bx*128 + r)*DTRANK + cel;
  #pragma unroll
  for (int p=0;p<8;p++){
    async16(gA + (long)p*16*DTRANK, ldsc + p*4096 + t*16);
    async16(gB + (long)p*16*DTRANK, ldsc + 32768 + p*4096 + t*16);
  }

  const int wave = t>>6, lane = t&63;
  const int wr = (wave>>1)*64, wc = (wave&1)*64;
  const int fr = lane&15, fc = lane>>4;

  fvec4 acc[4][4];
  #pragma unroll
  for(int i=0;i<4;i++){
    #pragma unroll
    for(int j=0;j<4;j++) acc[i][j] = (fvec4)(0.f);
  }

  asm volatile("s_waitcnt vmcnt(0)" ::: "memory");
  __builtin_amdgcn_s_barrier();
  __builtin_amdgcn_sched_barrier(0);

  #pragma unroll
  for (int s=0;s<4;s++){
    const int xsw = (((4*s + fc) ^ fr) << 4);
    bf16x8 af[4], bv[4];
    #pragma unroll
    for (int i=0;i<4;i++) af[i] = *(const bf16x8*)(ldsc + (wr + i*16 + fr)*256 + xsw);
    #pragma unroll
    for (int j=0;j<4;j++) bv[j] = *(const bf16x8*)(ldsc + 32768 + (wc + j*16 + fr)*256 + xsw);
    #pragma unroll
    for (int i=0;i<4;i++){
      #pragma unroll
      for (int j=0;j<4;j++)
        acc[i][j] = __builtin_amdgcn_mfma_f32_16x16x32_bf16(af[i], bv[j], acc[i][j], 0,0,0);
    }
  }

  const long crow0 = (long)by*128 + wr;
  const int  ccol0 = bx*128 + wc;
  float bs[4];
  #pragma unroll
  for (int j=0;j<4;j++) bs[j] = bias[ccol0 + j*16 + fr];
  #pragma unroll
  for(int i=0;i<4;i++){
    #pragma unroll
    for(int j=0;j<4;j++){
      #pragma unroll
      for(int q=0;q<4;q++){
        long rg = crow0 + i*16 + fc*4 + q;
        int  cg = ccol0 + j*16 + fr;
        float x = acc[i][j][q] + bs[j];
        float sp = (x > 20.f) ? x : log1pf(__expf(x));
        Cb[rg*DINNER + cg] = f2bf(sp);
      }
    }
  }
}

// ---------------- m97-style 128x128 GEMM: x_proj split-K ----------------
__global__ __launch_bounds__(256) void gemm_bt4(
    const unsigned short* __restrict__ A,
    const unsigned short* __restrict__ B,
    int lda, int Kloop, int Nreal,
    float* __restrict__ Cf,
    int ldc)
{
  __shared__ __align__(16) unsigned short As[128*32];
  __shared__ __align__(16) unsigned short Bs[128*32];
  const int t = threadIdx.x;
  const int bx = blockIdx.x, by = blockIdx.y;
  const long koff = (long)blockIdx.z * Kloop;
  const int wave = t>>6, lane = t&63;
  const int wr = (wave>>1)*64, wc = (wave&1)*64;
  const int fr = lane&15, fc = lane>>4;
  fvec4 acc[4][4];
  #pragma unroll
  for(int i=0;i<4;i++){
    #pragma unroll
    for(int j=0;j<4;j++){ acc[i][j] = (fvec4)(0.f); }
  }
  const int srow = t>>2;
  const int scol = (t&3)*8;
  long rowA = (long)by*128 + srow;
  int rB0 = bx*128 + srow;      if (rB0 > Nreal-1) rB0 = Nreal-1;
  int rB1 = bx*128 + 64 + srow; if (rB1 > Nreal-1) rB1 = Nreal-1;
  const unsigned short* gA0 = A + rowA*(long)lda + scol + koff;
  const unsigned short* gA1 = gA0 + 64L*lda;
  const unsigned short* gB0 = B + (long)rB0*lda + scol + koff;
  const unsigned short* gB1 = B + (long)rB1*lda + scol + koff;
  unsigned short* lA0 = &As[t*8];
  unsigned short* lA1 = &As[2048 + t*8];
  unsigned short* lB0 = &Bs[t*8];
  unsigned short* lB1 = &Bs[2048 + t*8];

  for (int k0 = 0; k0 < Kloop; k0 += 32){
    async16(gA0 + k0, lA0);
    async16(gA1 + k0, lA1);
    async16(gB0 + k0, lB0);
    async16(gB1 + k0, lB1);
    __syncthreads();
    bf16x8 af[4], bv[4];
    #pragma unroll
    for(int i=0;i<4;i++){
      af[i] = *(const bf16x8*)&As[(wr + i*16 + fr)*32 + fc*8];
      bv[i] = *(const bf16x8*)&Bs[(wc + i*16 + fr)*32 + fc*8];
    }
    #pragma unroll
    for(int i=0;i<4;i++){
      #pragma unroll
      for(int j=0;j<4;j++){
        acc[i][j] = __builtin_amdgcn_mfma_f32_16x16x32_bf16(af[i], bv[j], acc[i][j], 0,0,0);
      }
    }
    __syncthreads();
  }

  const long crow0 = (long)by*128 + wr;
  const int ccol0 = bx*128 + wc;
  float* Cfz = Cf + (long)blockIdx.z * MROWS * ldc;
  #pragma unroll
  for(int i=0;i<4;i++){
    #pragma unroll
    for(int j=0;j<4;j++){
      #pragma unroll
      for(int q=0;q<4;q++){
        long rg = crow0 + i*16 + fc*4 + q;
        int  cg = ccol0 + j*16 + fr;
        if (cg < Nreal) Cfz[rg*ldc + cg] = acc[i][j][q];
      }
    }
  }
}

// ---------------- reduce x_proj partials + emit dtr bf16 ----------------
__global__ void reduce_xproj(const float* __restrict__ part,
                             float* __restrict__ xdbl,
                             unsigned short* __restrict__ dtr){
  int i = blockIdx.x*256 + threadIdx.x;
  long base = (long)i*4;
  fvec4 s = *(const fvec4*)&part[base];
  #pragma unroll
  for (int z=1; z<4; z++){
    fvec4 p = *(const fvec4*)&part[(long)z*MROWS*160 + base];
    s[0]+=p[0]; s[1]+=p[1]; s[2]+=p[2]; s[3]+=p[3];
  }
  *(fvec4*)&xdbl[base] = s;
  long mrow = base / 160;
  int c = (int)(base - mrow*160);
  if (c < DTRANK){
    usvec4 o; o[0]=f2bf(s[0]); o[1]=f2bf(s[1]); o[2]=f2bf(s[2]); o[3]=f2bf(s[3]);
    *(usvec4*)&dtr[mrow*DTRANK + c] = o;
  }
}

// ------- depthwise causal conv(4) + bias + SiLU (+ fused conv_state) -------
__global__ __launch_bounds__(256) void conv_silu_kernel(
    const unsigned short* __restrict__ xb, const float* __restrict__ w,
    const float* __restrict__ bias, unsigned short* __restrict__ ub,
    float* __restrict__ cs_out)
{
  int gid = blockIdx.x*256 + threadIdx.x;
  int d0 = (gid & 511)*8;
  long m = gid >> 9;
  int l = (int)(m & (SEQ-1));
  fvec4 w4[8];
  #pragma unroll
  for(int k=0;k<8;k++) w4[k] = *(const fvec4*)&w[(d0+k)*4];
  float acc[8];
  fvec4 b0 = *(const fvec4*)&bias[d0];
  fvec4 b1 = *(const fvec4*)&bias[d0+4];
  acc[0]=b0[0];acc[1]=b0[1];acc[2]=b0[2];acc[3]=b0[3];
  acc[4]=b1[0];acc[5]=b1[1];acc[6]=b1[2];acc[7]=b1[3];
  float xcur[8];
  #pragma unroll
  for(int j=0;j<4;j++){
    int lj = l-3+j;
    if (lj >= 0){
      ivec4 xv = *(const ivec4*)&xb[(m-3+j)*DINNER + d0];
      float xsv[8];
      #pragma unroll
      for(int q=0;q<4;q++){
        unsigned int wd = (unsigned int)xv[q];
        xsv[2*q]   = bf2f((unsigned short)(wd & 0xffffu));
        xsv[2*q+1] = bf2f((unsigned short)(wd >> 16));
      }
      #pragma unroll
      for(int k=0;k<8;k++) acc[k] += xsv[k]*w4[k][j];
      if (j==3){
        #pragma unroll
        for(int k=0;k<8;k++) xcur[k] = xsv[k];
      }
    }
  }
  if (l >= SEQ-4){
    int b = (int)(m >> 11);
    int jj = l - (SEQ-4);
    #pragma unroll
    for(int k=0;k<8;k++) cs_out[b*16384 + (d0+k)*4 + jj] = xcur[k];
  }
  ivec4 ov;
  #pragma unroll
  for(int q=0;q<4;q++){
    float y0 = acc[2*q]  * sigf(acc[2*q]);
    float y1 = acc[2*q+1]* sigf(acc[2*q+1]);
    ov[q] = (int)((unsigned)f2bf(y0) | ((unsigned)f2bf(y1) << 16));
  }
  *(ivec4*)&ub[m*DINNER + d0] = ov;
}

// ---- exp(dl*a[n]) for a[n] == -(n+1): powers of e1=exp(-dl) ----
__device__ __forceinline__ void exp_powers(float dl, float* e){
  float e1 = __expf(-dl);
  float p2 = e1*e1, p3 = p2*e1, p4 = p2*p2;
  float p5 = p4*e1, p6 = p4*p2, p7 = p4*p3, p8 = p4*p4;
  e[0]=e1; e[1]=p2; e[2]=p3; e[3]=p4; e[4]=p5; e[5]=p6; e[6]=p7; e[7]=p8;
  e[8]=p8*e1; e[9]=p8*p2; e[10]=p8*p3; e[11]=p8*p4;
  e[12]=p8*p5; e[13]=p8*p6; e[14]=p8*p7; e[15]=p8*p8;
}

// ================= chunked parallel scan (NCHUNK=32, LC=64) =================
__global__ __launch_bounds__(256) void scan_part1(
    const unsigned short* __restrict__ delta_b,
    const unsigned short* __restrict__ u_b,
    const float* __restrict__ xdbl,
    const float* __restrict__ Amat,
    float* __restrict__ S,
    float* __restrict__ sdelta)
{
  const int t = threadIdx.x;
  const int blk = blockIdx.x;
  const int c = blk & (NCHUNK-1), b = (blk>>5)&3, d = (blk>>7)*256 + t;
  float a[16], s[16];
  #pragma unroll
  for (int n=0;n<16;n++){ a[n] = Amat[n*DINNER+d]; s[n]=0.f; }
  bool powA = true;
  #pragma unroll
  for (int n=0;n<16;n++) powA = powA && (a[n] == -(float)(n+1));
  float sd = 0.f;
  const long mbase = (long)b*SEQ + c*LC;

#define S1_BODY(EXPR_E) \
  for (int l=0;l<LC;l++){ \
    long m = mbase + l; \
    float dl = bf2f(delta_b[m*DINNER+d]); \
    float ul = bf2f(u_b[m*DINNER+d]); \
    const float* xb = &xdbl[m*160 + 128]; \
    float dbu = dl*ul; \
    sd += dl; \
    float e[16]; EXPR_E; \
    _Pragma("unroll") \
    for (int g=0; g<4; g++){ \
      fvec4 Bg = *(const fvec4*)(xb + 4*g); \
      _Pragma("unroll") \
      for (int q=0;q<4;q++){ \
        int n = g*4+q; \
        s[n] = e[n]*s[n] + Bg[q]*dbu; \
      } \
    } \
  }

  if (powA){
    S1_BODY(exp_powers(dl, e))
  } else {
    S1_BODY({ _Pragma("unroll") for (int n=0;n<16;n++) e[n] = __expf(dl*a[n]); })
  }
#undef S1_BODY

  const long base = ((long)(b*NCHUNK + c)*DSTATE)*DINNER + d;
  #pragma unroll
  for (int n=0;n<16;n++) S[base + (long)n*DINNER] = s[n];
  sdelta[(long)(b*NCHUNK+c)*DINNER + d] = sd;
}

__global__ __launch_bounds__(256) void scan_part2(
    float* SX,
    const float* __restrict__ sdelta,
    const float* __restrict__ Amat,
    float* __restrict__ last_state)
{
  int id = blockIdx.x*256 + threadIdx.x;
  int d = id & (DINNER-1);
  int n = (id>>12) & 15;
  int b = id>>16;
  float a = Amat[n*DINNER+d];
  float X = 0.f;
  #pragma unroll
  for (int c=0;c<NCHUNK;c++){
    long sb = ((long)(b*NCHUNK+c)*DSTATE + n)*DINNER + d;
    float Sc = SX[sb];
    float sd = sdelta[(long)(b*NCHUNK+c)*DINNER + d];
    SX[sb] = X;
    X = __expf(a*sd)*X + Sc;
  }
  last_state[((long)b*DSTATE + n)*DINNER + d] = X;
}

__global__ __launch_bounds__(256) void scan_part3(
    const unsigned short* __restrict__ delta_b,
    const unsigned short* __restrict__ u_b,
    const unsigned short* __restrict__ z_b,
    const float* __restrict__ xdbl,
    const float* __restrict__ Amat,
    const float* __restrict__ Dvec,
    const float* __restrict__ Xin,
    unsigned short* __restrict__ y_b)
{
  const int t = threadIdx.x;
  const int blk = blockIdx.x;
  const int c = blk & (NCHUNK-1), b = (blk>>5)&3, d = (blk>>7)*256 + t;
  float a[16], s[16];
  const long xb0 = ((long)(b*NCHUNK + c)*DSTATE)*DINNER + d;
  #pragma unroll
  for (int n=0;n<16;n++){
    a[n] = Amat[n*DINNER+d];
    s[n] = Xin[xb0 + (long)n*DINNER];
  }
  bool powA = true;
  #pragma unroll
  for (int n=0;n<16;n++) powA = powA && (a[n] == -(float)(n+1));
  const float Dd = Dvec[d];
  const long mbase = (long)b*SEQ + c*LC;

#define S3_BODY(EXPR_E) \
  for (int l=0;l<LC;l++){ \
    long m = mbase + l; \
    float dl = bf2f(delta_b[m*DINNER+d]); \
    float ul = bf2f(u_b[m*DINNER+d]); \
    float zl = bf2f(z_b[m*DINNER+d]); \
    const float* xb = &xdbl[m*160 + 128]; \
    float dbu = dl*ul; \
    float y = 0.f; \
    float e[16]; EXPR_E; \
    _Pragma("unroll") \
    for (int g=0; g<4; g++){ \
      fvec4 Bg = *(const fvec4*)(xb + 4*g); \
      fvec4 Cg = *(const fvec4*)(xb + 16 + 4*g); \
      _Pragma("unroll") \
      for (int q=0;q<4;q++){ \
        int n = g*4+q; \
        s[n] = e[n]*s[n] + Bg[q]*dbu; \
        y += Cg[q]*s[n]; \
      } \
    } \
    float yy = y + ul*Dd; \
    float zs = zl*sigf(zl); \
    y_b[m*DINNER+d] = f2bf(yy*zs); \
  }

  if (powA){
    S3_BODY(exp_powers(dl, e))
  } else {
    S3_BODY({ _Pragma("unroll") for (int n=0;n<16;n++) e[n] = __expf(dl*a[n]); })
  }
#undef S3_BODY
}

// ---------------- launcher ----------------
// Aliased 256 MiB layout:
//   Slot A [0,64M):    hs_b(32M)+w_in_b(32M) -> xpart(21M, step 5-6) ->
//                      delta(64M, step 7+)
//   Slot B [64,128M):  x(64M) -> after conv: wxp@64 wdt@66 wout@68 xdbl@84
//                      dtr@90 SX@92(32M, in-place) sdelta@124(2M)
//   Slot C [128,192M): z(64M)
//   Slot D [192,256M): u(64M) -> y written in-place by scan_part3
extern "C" void kernel_launch(void* const* d_in, const int* in_sizes, int n_in,
                              void* d_out, int out_size, void* d_ws, size_t ws_size,
                              hipStream_t stream) {
  const float* hs     = (const float*)d_in[0];
  const float* w_in   = (const float*)d_in[6];
  const float* conv_w = (const float*)d_in[7];
  const float* conv_b = (const float*)d_in[8];
  const float* w_xp   = (const float*)d_in[9];
  const float* w_dt   = (const float*)d_in[10];
  const float* dt_bias= (const float*)d_in[11];
  const float* Amat   = (const float*)d_in[12];
  const float* Dvec   = (const float*)d_in[13];
  const float* w_out  = (const float*)d_in[14];
  float* out = (float*)d_out;

  char* ws = (char*)d_ws;
  const size_t MiB = (size_t)1 << 20;

  unsigned short *hs_b, *w_in_b, *x_b, *z_b, *u_b, *delta_b;
  unsigned short *wxp_b, *wdt_b, *wout_b, *dtr_b, *y_b;
  float *xdbl, *SX, *sdelta, *xpart;

  if (ws_size >= 424*MiB){
    size_t off = 0;
    auto alloc = [&](size_t bytes)->void*{ void* p = ws + off; off += (bytes + 255) & ~(size_t)255; return p; };
    hs_b   = (unsigned short*)alloc((size_t)MROWS*DMODEL*2);
    w_in_b = (unsigned short*)alloc((size_t)2*DINNER*DMODEL*2);
    x_b    = (unsigned short*)alloc((size_t)MROWS*DINNER*2);
    z_b    = (unsigned short*)alloc((size_t)MROWS*DINNER*2);
    u_b    = (unsigned short*)alloc((size_t)MROWS*DINNER*2);
    delta_b= (unsigned short*)alloc((size_t)MROWS*DINNER*2);
    wxp_b  = (unsigned short*)alloc((size_t)160*DINNER*2);
    wdt_b  = (unsigned short*)alloc((size_t)DINNER*DTRANK*2);
    wout_b = (unsigned short*)alloc((size_t)DMODEL*DINNER*2);
    xdbl   = (float*)alloc((size_t)MROWS*160*4);
    dtr_b  = (unsigned short*)alloc((size_t)MROWS*DTRANK*2);
    SX     = (float*)alloc((size_t)NB*NCHUNK*DSTATE*DINNER*4);
    sdelta = (float*)alloc((size_t)NB*NCHUNK*DINNER*4);
    xpart  = (float*)alloc((size_t)4*MROWS*160*4);
    y_b    = x_b;
  } else {
    hs_b    = (unsigned short*)(ws + 0);
    w_in_b  = (unsigned short*)(ws + 32*MiB);
    xpart   = (float*)         (ws + 0);
    delta_b = (unsigned short*)(ws + 0);
    x_b     = (unsigned short*)(ws + 64*MiB);
    wxp_b   = (unsigned short*)(ws + 64*MiB);
    wdt_b   = (unsigned short*)(ws + 66*MiB);
    wout_b  = (unsigned short*)(ws + 68*MiB);
    xdbl    = (float*)         (ws + 84*MiB);
    dtr_b   = (unsigned short*)(ws + 90*MiB);
    SX      = (float*)         (ws + 92*MiB);
    sdelta  = (float*)         (ws + 124*MiB);
    z_b     = (unsigned short*)(ws + 128*MiB);
    u_b     = (unsigned short*)(ws + 192*MiB);
    y_b     = u_b;
  }

  // 1) converts needed for in_proj
  cvt2_kernel<<<(2*MROWS*DMODEL)/1024, 256, 0, stream>>>(hs, hs_b, w_in, w_in_b,
                                                         MROWS*DMODEL);
  // 2) in_proj
  gemm256<0><<<1024, 512, 0, stream>>>(hs_b, w_in_b, DMODEL, 32, 0,
                                       x_b, z_b, nullptr);
  // 3) conv + silu -> u, fused conv_state output
  conv_silu_kernel<<<(MROWS*512)/256, 256, 0, stream>>>(x_b, conv_w, conv_b, u_b,
                                                        out + (size_t)MROWS*DMODEL);
  // 4) weight converts
  {
    int na = 160*DINNER, nb = DINNER*DTRANK, nc = DMODEL*DINNER;
    int tot4 = (na+nb+nc)/4;
    cvt3_kernel<<<(tot4+255)/256, 256, 0, stream>>>(w_xp, wxp_b, na,
                                                    w_dt, wdt_b, nb,
                                                    w_out, wout_b, nc);
  }
  // 5) x_proj split-K x4 -> partials
  gemm_bt4<<<dim3(2,64,4), 256, 0, stream>>>(u_b, wxp_b, DINNER, 1024, 160,
                                             xpart, 160);
  // 6) reduce partials -> xdbl fp32 + dtr bf16
  reduce_xproj<<<(MROWS*160/4)/256, 256, 0, stream>>>(xpart, xdbl, dtr_b);
  // 7) dt_proj + softplus -> delta (single-stage K=128 kernel)
  dt128_kernel<<<dim3(32,64), 256, 0, stream>>>(dtr_b, wdt_b, dt_bias, delta_b);
  // 8) chunked scan
  scan_part1<<<2048, 256, 0, stream>>>(delta_b, u_b, xdbl, Amat, SX, sdelta);
  scan_part2<<<1024, 256, 0, stream>>>(SX, sdelta, Amat,
                                       out + (size_t)MROWS*DMODEL + NB*DINNER*4);
  scan_part3<<<2048, 256, 0, stream>>>(delta_b, u_b, z_b, xdbl, Amat, Dvec, SX, y_b);
  // 9) out_proj
  gemm256<3><<<256, 512, 0, stream>>>(y_b, wout_b, DINNER, 8, DMODEL,
                                      nullptr, nullptr, out);
}